// Round 8
// baseline (524.587 us; speedup 1.0000x reference)
//
#include <hip/hip_runtime.h>

// 2-layer GCN: h1 = relu(Anorm @ (x@w1) + b1); out = Anorm @ (h1@w2) + b2
// CSR-by-dst built per call; bf16 gather tables (f32 accumulate).
// R7->R8: histogram atomics go to 16 STRIPE-PRIVATE counter copies
// (stripe = blockIdx&15; with round-robin dispatch, blockIdx&7 ~ XCD ->
// counter lines stay XCD-local; same-address contention /16). A combine
// kernel folds copies into deg/dinv + per-node stripe-exclusive offsets;
// fill uses pos = rowptr[d] + cntoff[stripe][d] + rank[j].

constexpr int NS = 16;        // counter stripes
constexpr int CHUNK = 2048;   // edges per hist block (256 thr x 8)

// ---------------- edge dtype detect (int32 vs int64) ----------------
__global__ void detect_i64(const int* __restrict__ idx32, int* __restrict__ flag) {
    int v = idx32[2 * threadIdx.x + 1];
    unsigned long long b = __ballot(v != 0);
    if (threadIdx.x == 0) flag[0] = (b == 0ULL) ? 1 : 0;
}

__device__ __forceinline__ int load_idx(const void* edges, size_t i, int is64) {
    return is64 ? (int)((const long long*)edges)[i] : ((const int*)edges)[i];
}

__device__ __forceinline__ int clampN(int v, int N) {
    return ((unsigned)v < (unsigned)N) ? v : 0;
}

__device__ __forceinline__ ushort f2bf(float f) {  // RNE f32->bf16
    unsigned x = __float_as_uint(f);
    return (ushort)((x + 0x7FFF + ((x >> 16) & 1)) >> 16);
}
__device__ __forceinline__ float bf_lo(unsigned u) { return __uint_as_float(u << 16); }
__device__ __forceinline__ float bf_hi(unsigned u) { return __uint_as_float(u & 0xFFFF0000u); }
__device__ __forceinline__ float bf1(ushort u) { return __uint_as_float((unsigned)u << 16); }

// ------- striped histogram + rank capture (block-chunked, 8 edges/thread) ---
// Block b owns edges [b*CHUNK, b*CHUNK+CHUNK); stripe = b & (NS-1).
__global__ void hist_kernel(const void* __restrict__ edges, int E,
                            const int* __restrict__ flag, int* __restrict__ cnt,
                            int* __restrict__ rank, int N) {
    int b = blockIdx.x;
    int base = b * CHUNK + threadIdx.x;
    int* __restrict__ c = cnt + (size_t)(b & (NS - 1)) * N;
    int is64 = flag[0];
    int d[8];
    bool ok[8];
#pragma unroll
    for (int u = 0; u < 8; ++u) {
        int j = base + u * 256;
        ok[u] = j < E;
        d[u] = clampN(load_idx(edges, (size_t)E + (ok[u] ? j : 0), is64), N);
    }
    int r[8];
#pragma unroll
    for (int u = 0; u < 8; ++u)
        if (ok[u]) r[u] = atomicAdd(&c[d[u]], 1);
#pragma unroll
    for (int u = 0; u < 8; ++u)
        if (ok[u]) rank[base + u * 256] = r[u];
}

// ------- combine stripes: exclusive stripe offsets + deg + dinv -------
__global__ void combine_kernel(int* __restrict__ cnt, int* __restrict__ deg,
                               float* __restrict__ dinv, int N) {
    int d = blockIdx.x * blockDim.x + threadIdx.x;
    if (d >= N) return;
    int t[NS];
#pragma unroll
    for (int s = 0; s < NS; ++s) t[s] = cnt[(size_t)s * N + d];
    int run = 0;
#pragma unroll
    for (int s = 0; s < NS; ++s) { int v = t[s]; cnt[(size_t)s * N + d] = run; run += v; }
    deg[d] = run;
    dinv[d] = rsqrtf((float)(run + 1));  // +1 for self-loop
}

// ---------------- 3-kernel exclusive scan over deg -> rowptr ----------------
__global__ void scan_partials(const int* __restrict__ deg, int* __restrict__ partials, int N) {
    __shared__ int sm[256];
    int t = threadIdx.x, i = blockIdx.x * 256 + t;
    sm[t] = (i < N) ? deg[i] : 0;
    __syncthreads();
    for (int off = 128; off > 0; off >>= 1) {
        if (t < off) sm[t] += sm[t + off];
        __syncthreads();
    }
    if (t == 0) partials[blockIdx.x] = sm[0];
}

__global__ void scan_scan(int* __restrict__ partials, int NB) {  // 1 block, 512 thr
    __shared__ int sm[512];
    int t = threadIdx.x;
    int v = (t < NB) ? partials[t] : 0;
    sm[t] = v; __syncthreads();
    for (int off = 1; off < 512; off <<= 1) {
        int x = sm[t];
        int y = (t >= off) ? sm[t - off] : 0;
        __syncthreads();
        sm[t] = x + y;
        __syncthreads();
    }
    if (t < NB) partials[t] = (t == 0) ? 0 : sm[t - 1];  // exclusive
}

__global__ void scan_write(const int* __restrict__ deg, const int* __restrict__ partials,
                           int* __restrict__ rowptr, int N, int E) {
    __shared__ int sm[256];
    int t = threadIdx.x, b = blockIdx.x, i = b * 256 + t;
    int v = (i < N) ? deg[i] : 0;
    sm[t] = v; __syncthreads();
    for (int off = 1; off < 256; off <<= 1) {
        int x = sm[t];
        int y = (t >= off) ? sm[t - off] : 0;
        __syncthreads();
        sm[t] = x + y;
        __syncthreads();
    }
    int ex = partials[b] + sm[t] - v;  // exclusive
    if (i < N) rowptr[i] = ex;
    if (i == 0 && b == 0) rowptr[N] = E;
}

// ------- atomic-free fill: colx[rowptr[d] + cntoff[s][d] + rank] = s -------
__global__ void fill_kernel(const void* __restrict__ edges, int E, int T,
                            const int* __restrict__ flag,
                            const int* __restrict__ rowptr,
                            const int* __restrict__ cnt,
                            const int* __restrict__ rank,
                            int* __restrict__ colx, int N) {
    int i = blockIdx.x * blockDim.x + threadIdx.x;
    if (i >= T) return;  // exact partition
    int is64 = flag[0];
    int s[4], d[4], r[4], rp[4], co[4];
    bool ok[4];
#pragma unroll
    for (int u = 0; u < 4; ++u) {
        int j = i + u * T;
        ok[u] = j < E;
        int jj = ok[u] ? j : 0;
        s[u] = clampN(load_idx(edges, (size_t)jj, is64), N);
        d[u] = clampN(load_idx(edges, (size_t)E + jj, is64), N);
        r[u] = rank[jj];
        int st = (jj / CHUNK) & (NS - 1);
        rp[u] = rowptr[d[u]];
        co[u] = cnt[(size_t)st * N + d[u]];
    }
#pragma unroll
    for (int u = 0; u < 4; ++u)
        if (ok[u]) colx[rp[u] + co[u] + r[u]] = s[u];
}

// ------- GEMM: G = bf16( dinv .* (X @ W) ), K=128 fixed -------
__global__ __launch_bounds__(256) void gemm_scale(
    const float* __restrict__ X, const float* __restrict__ W,
    const float* __restrict__ dinv, ushort* __restrict__ G, int M, int Ncols) {
    constexpr int K = 128;
    __shared__ float xT[K][64];   // [k][row]
    __shared__ float ws[K][64];   // [k][col]
    const int t = threadIdx.x;
    const int m0 = blockIdx.x * 64;
    const int c0 = blockIdx.y * 64;

    {
        int cl = (t & 15) * 4;
        int k0 = t >> 4;
        for (int kk = 0; kk < K; kk += 16) {
            int k = k0 + kk;
            float4 wv = *(const float4*)&W[(size_t)k * Ncols + c0 + cl];
            *(float4*)&ws[k][cl] = wv;
        }
    }
    {
        int r = t & 63, cg = t >> 6;
        int row = m0 + r;
        bool valid = row < M;
        const float* xrow = &X[(size_t)(valid ? row : (M - 1)) * K];
        for (int cc = 0; cc < 8; ++cc) {
            int c = cg * 4 + cc * 16;
            float4 v;
            if (valid) v = *(const float4*)&xrow[c];
            else { v.x = v.y = v.z = v.w = 0.f; }
            xT[c + 0][r] = v.x; xT[c + 1][r] = v.y;
            xT[c + 2][r] = v.z; xT[c + 3][r] = v.w;
        }
    }
    __syncthreads();

    const int tc = (t & 15) * 4;
    const int tr = (t >> 4) * 4;
    float acc[4][4] = {};
#pragma unroll 8
    for (int k = 0; k < K; ++k) {
        float4 av = *(const float4*)&xT[k][tr];
        float4 bv = *(const float4*)&ws[k][tc];
        float a[4] = {av.x, av.y, av.z, av.w};
        float b[4] = {bv.x, bv.y, bv.z, bv.w};
#pragma unroll
        for (int i = 0; i < 4; ++i)
#pragma unroll
            for (int j = 0; j < 4; ++j)
                acc[i][j] = fmaf(a[i], b[j], acc[i][j]);
    }

#pragma unroll
    for (int i = 0; i < 4; ++i) {
        int row = m0 + tr + i;
        if (row < M) {
            float d = dinv[row];
            ushort4 o;
            o.x = f2bf(acc[i][0] * d); o.y = f2bf(acc[i][1] * d);
            o.z = f2bf(acc[i][2] * d); o.w = f2bf(acc[i][3] * d);
            *(ushort4*)&G[(size_t)row * Ncols + c0 + tc] = o;
        }
    }
}

// ------- aggregation: out[i] = dinv[i]*(sum_nbr g[src] + g[i]) + b -------
// One wave per node; bf16 gather table, f32 accumulate; fully predicated
// UNR-deep gather pipeline; gathered indices clamped to [0,N).
template <int F, bool RELU, int UNR>
__global__ __launch_bounds__(256) void agg_kernel(
    const ushort* __restrict__ G, const int* __restrict__ rowptr,
    const int* __restrict__ colx, const float* __restrict__ dinv,
    const float* __restrict__ bias, float* __restrict__ Out, int N) {
    int wid = (int)((blockIdx.x * 256 + threadIdx.x) >> 6);
    int lane = threadIdx.x & 63;
    if (wid >= N) return;
    int s = rowptr[wid], e = rowptr[wid + 1];

    if constexpr (F == 128) {
        const unsigned* gp = (const unsigned*)G;     // row = 64 dwords (2 bf16 each)
        unsigned su = gp[((size_t)wid << 6) + lane]; // self-loop term
        float ax = bf_lo(su), ay = bf_hi(su);
        float ax2 = 0.f, ay2 = 0.f;
        for (int j = s; j < e; j += UNR) {
            int c[UNR];
            float w[UNR];
#pragma unroll
            for (int u = 0; u < UNR; ++u) {
                int jj = j + u;
                bool m = jj < e;
                w[u] = m ? 1.f : 0.f;
                c[u] = clampN(colx[m ? jj : (e - 1)], N);
            }
            unsigned v[UNR];
#pragma unroll
            for (int u = 0; u < UNR; ++u) v[u] = gp[((size_t)c[u] << 6) + lane];
#pragma unroll
            for (int u = 0; u < UNR; u += 2) {
                ax  = fmaf(w[u],     bf_lo(v[u]),     ax);
                ay  = fmaf(w[u],     bf_hi(v[u]),     ay);
                ax2 = fmaf(w[u + 1], bf_lo(v[u + 1]), ax2);
                ay2 = fmaf(w[u + 1], bf_hi(v[u + 1]), ay2);
            }
        }
        ax += ax2; ay += ay2;
        float d = dinv[wid];
        float2 bv = *(const float2*)&bias[lane * 2];
        float ox = fmaf(d, ax, bv.x);
        float oy = fmaf(d, ay, bv.y);
        if (RELU) { ox = fmaxf(ox, 0.f); oy = fmaxf(oy, 0.f); }
        float2 o; o.x = ox; o.y = oy;
        *(float2*)&Out[(size_t)wid * F + lane * 2] = o;
    } else {  // F == 64
        const ushort* gp = G;                        // row = 64 bf16
        float acc = bf1(gp[((size_t)wid << 6) + lane]);  // self
        float acc2 = 0.f;
        for (int j = s; j < e; j += UNR) {
            int c[UNR];
            float w[UNR];
#pragma unroll
            for (int u = 0; u < UNR; ++u) {
                int jj = j + u;
                bool m = jj < e;
                w[u] = m ? 1.f : 0.f;
                c[u] = clampN(colx[m ? jj : (e - 1)], N);
            }
            ushort v[UNR];
#pragma unroll
            for (int u = 0; u < UNR; ++u) v[u] = gp[((size_t)c[u] << 6) + lane];
#pragma unroll
            for (int u = 0; u < UNR; u += 2) {
                acc  = fmaf(w[u],     bf1(v[u]),     acc);
                acc2 = fmaf(w[u + 1], bf1(v[u + 1]), acc2);
            }
        }
        acc += acc2;
        float o = fmaf(dinv[wid], acc, bias[lane]);
        if (RELU) o = fmaxf(o, 0.f);
        Out[(size_t)wid * F + lane] = o;
    }
}

extern "C" void kernel_launch(void* const* d_in, const int* in_sizes, int n_in,
                              void* d_out, int out_size, void* d_ws, size_t ws_size,
                              hipStream_t stream) {
    const float* x  = (const float*)d_in[0];
    const void*  ei = d_in[1];
    const float* w1 = (const float*)d_in[2];
    const float* b1 = (const float*)d_in[3];
    const float* w2 = (const float*)d_in[4];
    const float* b2 = (const float*)d_in[5];
    float* out = (float*)d_out;

    const int N  = in_sizes[0] / 128;   // 100000
    const int E  = in_sizes[1] / 2;     // 3200000
    const int NB = (N + 255) / 256;

    char* p = (char*)d_ws;
    auto carve = [&](size_t bytes) {
        void* r = (void*)p;
        p += (bytes + 255) & ~(size_t)255;
        return r;
    };
    int*    cnt      = (int*)carve((size_t)NS * N * 4);  // striped counters
    int*    deg      = (int*)carve((size_t)N * 4);
    int*    rowptr   = (int*)carve((size_t)(N + 1) * 4);
    int*    partials = (int*)carve(512 * 4);
    int*    flag     = (int*)carve(256);
    float*  dinv     = (float*)carve((size_t)N * 4);
    int*    colx     = (int*)carve((size_t)E * 4);
    ushort* g1       = (ushort*)carve((size_t)N * 128 * 2);  // bf16 gather table
    float*  a1       = (float*)carve((size_t)N * 128 * 4);
    ushort* g2       = g1;        // g1 dead after agg1; reuse (N*64*2 fits)
    int*    rank     = (int*)a1;  // rank dead before agg1 writes a1

    const int nbH = (E + CHUNK - 1) / CHUNK;  // hist: block-chunked
    const int T4 = (E + 3) / 4;               // fill: 4 edges/thread
    const int nb4 = (T4 + 255) / 256;

    hipMemsetAsync(cnt, 0, (size_t)NS * N * 4, stream);
    detect_i64<<<1, 64, 0, stream>>>((const int*)ei, flag);
    hist_kernel<<<nbH, 256, 0, stream>>>(ei, E, flag, cnt, rank, N);
    combine_kernel<<<NB, 256, 0, stream>>>(cnt, deg, dinv, N);
    scan_partials<<<NB, 256, 0, stream>>>(deg, partials, N);
    scan_scan<<<1, 512, 0, stream>>>(partials, NB);
    scan_write<<<NB, 256, 0, stream>>>(deg, partials, rowptr, N, E);
    fill_kernel<<<nb4, 256, 0, stream>>>(ei, E, T4, flag, rowptr, cnt, rank, colx, N);

    dim3 grid1((N + 63) / 64, 2);
    gemm_scale<<<grid1, 256, 0, stream>>>(x, w1, dinv, g1, N, 128);
    agg_kernel<128, true, 16><<<(N + 3) / 4, 256, 0, stream>>>(g1, rowptr, colx, dinv, b1, a1, N);

    dim3 grid2((N + 63) / 64, 1);
    gemm_scale<<<grid2, 256, 0, stream>>>(a1, w2, dinv, g2, N, 64);
    agg_kernel<64, false, 16><<<(N + 3) / 4, 256, 0, stream>>>(g2, rowptr, colx, dinv, b2, out, N);
}

// Round 9
// 384.421 us; speedup vs baseline: 1.3646x; 1.3646x over previous
//
#include <hip/hip_runtime.h>

// 2-layer GCN: h1 = relu(Anorm @ (x@w1) + b1); out = Anorm @ (h1@w2) + b2
// bf16 gather tables (f32 accumulate). R8->R9: CSR build is now a fully
// ATOMIC-FREE (global) bucket sort -- R8 proved device atomics-with-return
// are capped at ~10/cy device-wide regardless of striping. Pipeline:
//   K1 bucket-count (LDS hist) -> K2 scan of cnt[bin][blk] (bin-major) ->
//   K3 bucketed scatter (LDS cursors) -> K4 per-bucket CSR (LDS count+scan,
//   writes deg/dinv/rowptr/colx directly). Only LDS atomics are used.

constexpr int B = 1024;       // dst-range buckets
constexpr int KB = 256;       // blocks in K1/K3

// ---------------- edge dtype detect (int32 vs int64) ----------------
__global__ void detect_i64(const int* __restrict__ idx32, int* __restrict__ flag) {
    int v = idx32[2 * threadIdx.x + 1];
    unsigned long long b = __ballot(v != 0);
    if (threadIdx.x == 0) flag[0] = (b == 0ULL) ? 1 : 0;
}

__device__ __forceinline__ int load_idx(const void* edges, size_t i, int is64) {
    return is64 ? (int)((const long long*)edges)[i] : ((const int*)edges)[i];
}

__device__ __forceinline__ int clampN(int v, int N) {
    return ((unsigned)v < (unsigned)N) ? v : 0;
}

__device__ __forceinline__ ushort f2bf(float f) {  // RNE f32->bf16
    unsigned x = __float_as_uint(f);
    return (ushort)((x + 0x7FFF + ((x >> 16) & 1)) >> 16);
}
__device__ __forceinline__ float bf_lo(unsigned u) { return __uint_as_float(u << 16); }
__device__ __forceinline__ float bf_hi(unsigned u) { return __uint_as_float(u & 0xFFFF0000u); }
__device__ __forceinline__ float bf1(ushort u) { return __uint_as_float((unsigned)u << 16); }

// ---- K1: per-block bucket histogram. cnt[bin*KB + blk] (bin-major). ----
__global__ __launch_bounds__(256) void bucket_count(
    const void* __restrict__ edges, int E, int EPB, int NR,
    const int* __restrict__ flag, int* __restrict__ cnt, int N) {
    __shared__ int hist[B];
    int t = threadIdx.x, b = blockIdx.x;
    for (int k = t; k < B; k += 256) hist[k] = 0;
    __syncthreads();
    int is64 = flag[0];
    int start = b * EPB, end = min(E, start + EPB);
    for (int j = start + t; j < end; j += 256) {
        int d = clampN(load_idx(edges, (size_t)E + j, is64), N);
        atomicAdd(&hist[d / NR], 1);
    }
    __syncthreads();
    for (int k = t; k < B; k += 256) cnt[(size_t)k * KB + b] = hist[k];
}

// ---------------- 3-kernel exclusive scan (M = B*KB elements) ----------------
__global__ void scan_partials(const int* __restrict__ in, int* __restrict__ partials, int M) {
    __shared__ int sm[256];
    int t = threadIdx.x, i = blockIdx.x * 256 + t;
    sm[t] = (i < M) ? in[i] : 0;
    __syncthreads();
    for (int off = 128; off > 0; off >>= 1) {
        if (t < off) sm[t] += sm[t + off];
        __syncthreads();
    }
    if (t == 0) partials[blockIdx.x] = sm[0];
}

__global__ void scan_scan(int* __restrict__ partials, int NB) {  // 1 block, 1024 thr
    __shared__ int sm[1024];
    int t = threadIdx.x;
    int v = (t < NB) ? partials[t] : 0;
    sm[t] = v; __syncthreads();
    for (int off = 1; off < 1024; off <<= 1) {
        int x = sm[t];
        int y = (t >= off) ? sm[t - off] : 0;
        __syncthreads();
        sm[t] = x + y;
        __syncthreads();
    }
    if (t < NB) partials[t] = (t == 0) ? 0 : sm[t - 1];  // exclusive
}

__global__ void scan_write(const int* __restrict__ in, const int* __restrict__ partials,
                           int* __restrict__ out, int M) {
    __shared__ int sm[256];
    int t = threadIdx.x, b = blockIdx.x, i = b * 256 + t;
    int v = (i < M) ? in[i] : 0;
    sm[t] = v; __syncthreads();
    for (int off = 1; off < 256; off <<= 1) {
        int x = sm[t];
        int y = (t >= off) ? sm[t - off] : 0;
        __syncthreads();
        sm[t] = x + y;
        __syncthreads();
    }
    if (i < M) out[i] = partials[b] + sm[t] - v;  // exclusive
}

// ---- K3: bucketed scatter. LDS cursors from base[bin*KB+blk]; buck=(src,dst). ----
__global__ __launch_bounds__(256) void bucket_scatter(
    const void* __restrict__ edges, int E, int EPB, int NR,
    const int* __restrict__ flag, const int* __restrict__ base,
    int2* __restrict__ buck, int N) {
    __shared__ int cur[B];
    int t = threadIdx.x, b = blockIdx.x;
    for (int k = t; k < B; k += 256) cur[k] = base[(size_t)k * KB + b];
    __syncthreads();
    int is64 = flag[0];
    int start = b * EPB, end = min(E, start + EPB);
    for (int j = start + t; j < end; j += 256) {
        int s = clampN(load_idx(edges, (size_t)j, is64), N);
        int d = clampN(load_idx(edges, (size_t)E + j, is64), N);
        int pos = atomicAdd(&cur[d / NR], 1);
        buck[pos] = make_int2(s, d);
    }
}

// ---- K4: per-bucket CSR. LDS count + scan; writes deg/dinv/rowptr/colx. ----
__global__ __launch_bounds__(256) void bucket_csr(
    const int2* __restrict__ buck, const int* __restrict__ base, int E, int NR,
    float* __restrict__ dinv, int* __restrict__ rowptr,
    int* __restrict__ colx, int N) {
    __shared__ int hist[128];  // NR <= 128
    __shared__ int cnt0[128];
    __shared__ int cur[128];
    int t = threadIdx.x, b = blockIdx.x;
    if (b == 0 && t == 0) rowptr[N] = E;
    int d0 = b * NR;
    if (d0 >= N) return;
    int nr = min(NR, N - d0);
    int segbase = base[(size_t)b * KB];
    int segend = (b == B - 1) ? E : base[(size_t)(b + 1) * KB];

    if (t < 128) hist[t] = 0;
    __syncthreads();
    for (int j = segbase + t; j < segend; j += 256)
        atomicAdd(&hist[buck[j].y - d0], 1);
    __syncthreads();
    if (t < 128) cnt0[t] = hist[t];
    __syncthreads();
    // inclusive scan over 128 (Hillis-Steele)
    for (int off = 1; off < 128; off <<= 1) {
        int v = 0;
        if (t < 128 && t >= off) v = hist[t - off];
        __syncthreads();
        if (t < 128) hist[t] += v;
        __syncthreads();
    }
    if (t < 128) {
        int ex = hist[t] - cnt0[t];  // exclusive
        cur[t] = ex;
        if (t < nr) {
            rowptr[d0 + t] = segbase + ex;
            dinv[d0 + t] = rsqrtf((float)(cnt0[t] + 1));  // +1 self-loop
        }
    }
    __syncthreads();
    for (int j = segbase + t; j < segend; j += 256) {
        int2 e = buck[j];
        int pos = segbase + atomicAdd(&cur[e.y - d0], 1);
        colx[pos] = e.x;
    }
}

// ------- GEMM: G = bf16( dinv .* (X @ W) ), K=128 fixed -------
__global__ __launch_bounds__(256) void gemm_scale(
    const float* __restrict__ X, const float* __restrict__ W,
    const float* __restrict__ dinv, ushort* __restrict__ G, int M, int Ncols) {
    constexpr int K = 128;
    __shared__ float xT[K][64];   // [k][row]
    __shared__ float ws[K][64];   // [k][col]
    const int t = threadIdx.x;
    const int m0 = blockIdx.x * 64;
    const int c0 = blockIdx.y * 64;

    {
        int cl = (t & 15) * 4;
        int k0 = t >> 4;
        for (int kk = 0; kk < K; kk += 16) {
            int k = k0 + kk;
            float4 wv = *(const float4*)&W[(size_t)k * Ncols + c0 + cl];
            *(float4*)&ws[k][cl] = wv;
        }
    }
    {
        int r = t & 63, cg = t >> 6;
        int row = m0 + r;
        bool valid = row < M;
        const float* xrow = &X[(size_t)(valid ? row : (M - 1)) * K];
        for (int cc = 0; cc < 8; ++cc) {
            int c = cg * 4 + cc * 16;
            float4 v;
            if (valid) v = *(const float4*)&xrow[c];
            else { v.x = v.y = v.z = v.w = 0.f; }
            xT[c + 0][r] = v.x; xT[c + 1][r] = v.y;
            xT[c + 2][r] = v.z; xT[c + 3][r] = v.w;
        }
    }
    __syncthreads();

    const int tc = (t & 15) * 4;
    const int tr = (t >> 4) * 4;
    float acc[4][4] = {};
#pragma unroll 8
    for (int k = 0; k < K; ++k) {
        float4 av = *(const float4*)&xT[k][tr];
        float4 bv = *(const float4*)&ws[k][tc];
        float a[4] = {av.x, av.y, av.z, av.w};
        float b[4] = {bv.x, bv.y, bv.z, bv.w};
#pragma unroll
        for (int i = 0; i < 4; ++i)
#pragma unroll
            for (int j = 0; j < 4; ++j)
                acc[i][j] = fmaf(a[i], b[j], acc[i][j]);
    }

#pragma unroll
    for (int i = 0; i < 4; ++i) {
        int row = m0 + tr + i;
        if (row < M) {
            float d = dinv[row];
            ushort4 o;
            o.x = f2bf(acc[i][0] * d); o.y = f2bf(acc[i][1] * d);
            o.z = f2bf(acc[i][2] * d); o.w = f2bf(acc[i][3] * d);
            *(ushort4*)&G[(size_t)row * Ncols + c0 + tc] = o;
        }
    }
}

// ------- aggregation: out[i] = dinv[i]*(sum_nbr g[src] + g[i]) + b -------
// One wave per node; bf16 gather table, f32 accumulate; fully predicated
// UNR-deep gather pipeline; gathered indices clamped to [0,N).
template <int F, bool RELU, int UNR>
__global__ __launch_bounds__(256) void agg_kernel(
    const ushort* __restrict__ G, const int* __restrict__ rowptr,
    const int* __restrict__ colx, const float* __restrict__ dinv,
    const float* __restrict__ bias, float* __restrict__ Out, int N) {
    int wid = (int)((blockIdx.x * 256 + threadIdx.x) >> 6);
    int lane = threadIdx.x & 63;
    if (wid >= N) return;
    int s = rowptr[wid], e = rowptr[wid + 1];

    if constexpr (F == 128) {
        const unsigned* gp = (const unsigned*)G;     // row = 64 dwords (2 bf16 each)
        unsigned su = gp[((size_t)wid << 6) + lane]; // self-loop term
        float ax = bf_lo(su), ay = bf_hi(su);
        float ax2 = 0.f, ay2 = 0.f;
        for (int j = s; j < e; j += UNR) {
            int c[UNR];
            float w[UNR];
#pragma unroll
            for (int u = 0; u < UNR; ++u) {
                int jj = j + u;
                bool m = jj < e;
                w[u] = m ? 1.f : 0.f;
                c[u] = clampN(colx[m ? jj : (e - 1)], N);
            }
            unsigned v[UNR];
#pragma unroll
            for (int u = 0; u < UNR; ++u) v[u] = gp[((size_t)c[u] << 6) + lane];
#pragma unroll
            for (int u = 0; u < UNR; u += 2) {
                ax  = fmaf(w[u],     bf_lo(v[u]),     ax);
                ay  = fmaf(w[u],     bf_hi(v[u]),     ay);
                ax2 = fmaf(w[u + 1], bf_lo(v[u + 1]), ax2);
                ay2 = fmaf(w[u + 1], bf_hi(v[u + 1]), ay2);
            }
        }
        ax += ax2; ay += ay2;
        float d = dinv[wid];
        float2 bv = *(const float2*)&bias[lane * 2];
        float ox = fmaf(d, ax, bv.x);
        float oy = fmaf(d, ay, bv.y);
        if (RELU) { ox = fmaxf(ox, 0.f); oy = fmaxf(oy, 0.f); }
        float2 o; o.x = ox; o.y = oy;
        *(float2*)&Out[(size_t)wid * F + lane * 2] = o;
    } else {  // F == 64
        const ushort* gp = G;                        // row = 64 bf16
        float acc = bf1(gp[((size_t)wid << 6) + lane]);  // self
        float acc2 = 0.f;
        for (int j = s; j < e; j += UNR) {
            int c[UNR];
            float w[UNR];
#pragma unroll
            for (int u = 0; u < UNR; ++u) {
                int jj = j + u;
                bool m = jj < e;
                w[u] = m ? 1.f : 0.f;
                c[u] = clampN(colx[m ? jj : (e - 1)], N);
            }
            ushort v[UNR];
#pragma unroll
            for (int u = 0; u < UNR; ++u) v[u] = gp[((size_t)c[u] << 6) + lane];
#pragma unroll
            for (int u = 0; u < UNR; u += 2) {
                acc  = fmaf(w[u],     bf1(v[u]),     acc);
                acc2 = fmaf(w[u + 1], bf1(v[u + 1]), acc2);
            }
        }
        acc += acc2;
        float o = fmaf(dinv[wid], acc, bias[lane]);
        if (RELU) o = fmaxf(o, 0.f);
        Out[(size_t)wid * F + lane] = o;
    }
}

extern "C" void kernel_launch(void* const* d_in, const int* in_sizes, int n_in,
                              void* d_out, int out_size, void* d_ws, size_t ws_size,
                              hipStream_t stream) {
    const float* x  = (const float*)d_in[0];
    const void*  ei = d_in[1];
    const float* w1 = (const float*)d_in[2];
    const float* b1 = (const float*)d_in[3];
    const float* w2 = (const float*)d_in[4];
    const float* b2 = (const float*)d_in[5];
    float* out = (float*)d_out;

    const int N  = in_sizes[0] / 128;   // 100000
    const int E  = in_sizes[1] / 2;     // 3200000
    const int M  = B * KB;              // cnt matrix cells
    const int NR = (N + B - 1) / B;     // nodes per bucket (<=128)

    char* p = (char*)d_ws;
    auto carve = [&](size_t bytes) {
        void* r = (void*)p;
        p += (bytes + 255) & ~(size_t)255;
        return r;
    };
    int*    cnt      = (int*)carve((size_t)M * 4);
    int*    base     = (int*)carve((size_t)M * 4);
    int*    partials = (int*)carve(1024 * 4);
    int*    flag     = (int*)carve(256);
    int*    rowptr   = (int*)carve((size_t)(N + 1) * 4);
    float*  dinv     = (float*)carve((size_t)N * 4);
    int*    colx     = (int*)carve((size_t)E * 4);
    ushort* g1       = (ushort*)carve((size_t)N * 128 * 2);  // bf16 gather table
    float*  a1       = (float*)carve((size_t)N * 128 * 4);
    ushort* g2       = g1;          // g1 dead after agg1; reuse
    int2*   buck     = (int2*)a1;   // buck (E*8=25.6MB) dead before agg1 writes a1

    const int EPB = (E + KB - 1) / KB;  // edges per K1/K3 block
    const int NBS = M / 256;            // scan blocks (1024)

    detect_i64<<<1, 64, 0, stream>>>((const int*)ei, flag);
    bucket_count<<<KB, 256, 0, stream>>>(ei, E, EPB, NR, flag, cnt, N);
    scan_partials<<<NBS, 256, 0, stream>>>(cnt, partials, M);
    scan_scan<<<1, 1024, 0, stream>>>(partials, NBS);
    scan_write<<<NBS, 256, 0, stream>>>(cnt, partials, base, M);
    bucket_scatter<<<KB, 256, 0, stream>>>(ei, E, EPB, NR, flag, base, buck, N);
    bucket_csr<<<B, 256, 0, stream>>>(buck, base, E, NR, dinv, rowptr, colx, N);

    dim3 grid1((N + 63) / 64, 2);
    gemm_scale<<<grid1, 256, 0, stream>>>(x, w1, dinv, g1, N, 128);
    agg_kernel<128, true, 16><<<(N + 3) / 4, 256, 0, stream>>>(g1, rowptr, colx, dinv, b1, a1, N);

    dim3 grid2((N + 63) / 64, 1);
    gemm_scale<<<grid2, 256, 0, stream>>>(a1, w2, dinv, g2, N, 64);
    agg_kernel<64, false, 16><<<(N + 3) / 4, 256, 0, stream>>>(g2, rowptr, colx, dinv, b2, out, N);
}

// Round 10
// 360.150 us; speedup vs baseline: 1.4566x; 1.0674x over previous
//
#include <hip/hip_runtime.h>

// 2-layer GCN: h1 = relu(Anorm @ (x@w1) + b1); out = Anorm @ (h1@w2) + b2
// bf16 gather tables (f32 accumulate); atomic-free bucket-sort CSR (R9).
// R9->R10: agg inner loop de-predicated -- exact unrolled main loop (pure
// adds, no masks) + ONE masked UNR-wide tail batch per node. agg1 was
// VALU-issue-bound (VALUBusy 80%); this cuts ~3 VALU/edge.

constexpr int B = 1024;       // dst-range buckets
constexpr int KB = 256;       // blocks in K1/K3

// ---------------- edge dtype detect (int32 vs int64) ----------------
__global__ void detect_i64(const int* __restrict__ idx32, int* __restrict__ flag) {
    int v = idx32[2 * threadIdx.x + 1];
    unsigned long long b = __ballot(v != 0);
    if (threadIdx.x == 0) flag[0] = (b == 0ULL) ? 1 : 0;
}

__device__ __forceinline__ int load_idx(const void* edges, size_t i, int is64) {
    return is64 ? (int)((const long long*)edges)[i] : ((const int*)edges)[i];
}

__device__ __forceinline__ int clampN(int v, int N) {
    return ((unsigned)v < (unsigned)N) ? v : 0;
}

__device__ __forceinline__ ushort f2bf(float f) {  // RNE f32->bf16
    unsigned x = __float_as_uint(f);
    return (ushort)((x + 0x7FFF + ((x >> 16) & 1)) >> 16);
}
__device__ __forceinline__ float bf_lo(unsigned u) { return __uint_as_float(u << 16); }
__device__ __forceinline__ float bf_hi(unsigned u) { return __uint_as_float(u & 0xFFFF0000u); }
__device__ __forceinline__ float bf1(ushort u) { return __uint_as_float((unsigned)u << 16); }

// ---- K1: per-block bucket histogram. cnt[bin*KB + blk] (bin-major). ----
__global__ __launch_bounds__(256) void bucket_count(
    const void* __restrict__ edges, int E, int EPB, int NR,
    const int* __restrict__ flag, int* __restrict__ cnt, int N) {
    __shared__ int hist[B];
    int t = threadIdx.x, b = blockIdx.x;
    for (int k = t; k < B; k += 256) hist[k] = 0;
    __syncthreads();
    int is64 = flag[0];
    int start = b * EPB, end = min(E, start + EPB);
    for (int j = start + t; j < end; j += 256) {
        int d = clampN(load_idx(edges, (size_t)E + j, is64), N);
        atomicAdd(&hist[d / NR], 1);
    }
    __syncthreads();
    for (int k = t; k < B; k += 256) cnt[(size_t)k * KB + b] = hist[k];
}

// ---------------- 3-kernel exclusive scan (M = B*KB elements) ----------------
__global__ void scan_partials(const int* __restrict__ in, int* __restrict__ partials, int M) {
    __shared__ int sm[256];
    int t = threadIdx.x, i = blockIdx.x * 256 + t;
    sm[t] = (i < M) ? in[i] : 0;
    __syncthreads();
    for (int off = 128; off > 0; off >>= 1) {
        if (t < off) sm[t] += sm[t + off];
        __syncthreads();
    }
    if (t == 0) partials[blockIdx.x] = sm[0];
}

__global__ void scan_scan(int* __restrict__ partials, int NB) {  // 1 block, 1024 thr
    __shared__ int sm[1024];
    int t = threadIdx.x;
    int v = (t < NB) ? partials[t] : 0;
    sm[t] = v; __syncthreads();
    for (int off = 1; off < 1024; off <<= 1) {
        int x = sm[t];
        int y = (t >= off) ? sm[t - off] : 0;
        __syncthreads();
        sm[t] = x + y;
        __syncthreads();
    }
    if (t < NB) partials[t] = (t == 0) ? 0 : sm[t - 1];  // exclusive
}

__global__ void scan_write(const int* __restrict__ in, const int* __restrict__ partials,
                           int* __restrict__ out, int M) {
    __shared__ int sm[256];
    int t = threadIdx.x, b = blockIdx.x, i = b * 256 + t;
    int v = (i < M) ? in[i] : 0;
    sm[t] = v; __syncthreads();
    for (int off = 1; off < 256; off <<= 1) {
        int x = sm[t];
        int y = (t >= off) ? sm[t - off] : 0;
        __syncthreads();
        sm[t] = x + y;
        __syncthreads();
    }
    if (i < M) out[i] = partials[b] + sm[t] - v;  // exclusive
}

// ---- K3: bucketed scatter. LDS cursors from base[bin*KB+blk]; buck=(src,dst). ----
__global__ __launch_bounds__(256) void bucket_scatter(
    const void* __restrict__ edges, int E, int EPB, int NR,
    const int* __restrict__ flag, const int* __restrict__ base,
    int2* __restrict__ buck, int N) {
    __shared__ int cur[B];
    int t = threadIdx.x, b = blockIdx.x;
    for (int k = t; k < B; k += 256) cur[k] = base[(size_t)k * KB + b];
    __syncthreads();
    int is64 = flag[0];
    int start = b * EPB, end = min(E, start + EPB);
    for (int j = start + t; j < end; j += 256) {
        int s = clampN(load_idx(edges, (size_t)j, is64), N);
        int d = clampN(load_idx(edges, (size_t)E + j, is64), N);
        int pos = atomicAdd(&cur[d / NR], 1);
        buck[pos] = make_int2(s, d);
    }
}

// ---- K4: per-bucket CSR. LDS count + scan; writes deg/dinv/rowptr/colx. ----
__global__ __launch_bounds__(256) void bucket_csr(
    const int2* __restrict__ buck, const int* __restrict__ base, int E, int NR,
    float* __restrict__ dinv, int* __restrict__ rowptr,
    int* __restrict__ colx, int N) {
    __shared__ int hist[128];  // NR <= 128
    __shared__ int cnt0[128];
    __shared__ int cur[128];
    int t = threadIdx.x, b = blockIdx.x;
    if (b == 0 && t == 0) rowptr[N] = E;
    int d0 = b * NR;
    if (d0 >= N) return;
    int nr = min(NR, N - d0);
    int segbase = base[(size_t)b * KB];
    int segend = (b == B - 1) ? E : base[(size_t)(b + 1) * KB];

    if (t < 128) hist[t] = 0;
    __syncthreads();
    for (int j = segbase + t; j < segend; j += 256)
        atomicAdd(&hist[buck[j].y - d0], 1);
    __syncthreads();
    if (t < 128) cnt0[t] = hist[t];
    __syncthreads();
    // inclusive scan over 128 (Hillis-Steele)
    for (int off = 1; off < 128; off <<= 1) {
        int v = 0;
        if (t < 128 && t >= off) v = hist[t - off];
        __syncthreads();
        if (t < 128) hist[t] += v;
        __syncthreads();
    }
    if (t < 128) {
        int ex = hist[t] - cnt0[t];  // exclusive
        cur[t] = ex;
        if (t < nr) {
            rowptr[d0 + t] = segbase + ex;
            dinv[d0 + t] = rsqrtf((float)(cnt0[t] + 1));  // +1 self-loop
        }
    }
    __syncthreads();
    for (int j = segbase + t; j < segend; j += 256) {
        int2 e = buck[j];
        int pos = segbase + atomicAdd(&cur[e.y - d0], 1);
        colx[pos] = e.x;
    }
}

// ------- GEMM: G = bf16( dinv .* (X @ W) ), K=128 fixed -------
__global__ __launch_bounds__(256) void gemm_scale(
    const float* __restrict__ X, const float* __restrict__ W,
    const float* __restrict__ dinv, ushort* __restrict__ G, int M, int Ncols) {
    constexpr int K = 128;
    __shared__ float xT[K][64];   // [k][row]
    __shared__ float ws[K][64];   // [k][col]
    const int t = threadIdx.x;
    const int m0 = blockIdx.x * 64;
    const int c0 = blockIdx.y * 64;

    {
        int cl = (t & 15) * 4;
        int k0 = t >> 4;
        for (int kk = 0; kk < K; kk += 16) {
            int k = k0 + kk;
            float4 wv = *(const float4*)&W[(size_t)k * Ncols + c0 + cl];
            *(float4*)&ws[k][cl] = wv;
        }
    }
    {
        int r = t & 63, cg = t >> 6;
        int row = m0 + r;
        bool valid = row < M;
        const float* xrow = &X[(size_t)(valid ? row : (M - 1)) * K];
        for (int cc = 0; cc < 8; ++cc) {
            int c = cg * 4 + cc * 16;
            float4 v;
            if (valid) v = *(const float4*)&xrow[c];
            else { v.x = v.y = v.z = v.w = 0.f; }
            xT[c + 0][r] = v.x; xT[c + 1][r] = v.y;
            xT[c + 2][r] = v.z; xT[c + 3][r] = v.w;
        }
    }
    __syncthreads();

    const int tc = (t & 15) * 4;
    const int tr = (t >> 4) * 4;
    float acc[4][4] = {};
#pragma unroll 8
    for (int k = 0; k < K; ++k) {
        float4 av = *(const float4*)&xT[k][tr];
        float4 bv = *(const float4*)&ws[k][tc];
        float a[4] = {av.x, av.y, av.z, av.w};
        float b[4] = {bv.x, bv.y, bv.z, bv.w};
#pragma unroll
        for (int i = 0; i < 4; ++i)
#pragma unroll
            for (int j = 0; j < 4; ++j)
                acc[i][j] = fmaf(a[i], b[j], acc[i][j]);
    }

#pragma unroll
    for (int i = 0; i < 4; ++i) {
        int row = m0 + tr + i;
        if (row < M) {
            float d = dinv[row];
            ushort4 o;
            o.x = f2bf(acc[i][0] * d); o.y = f2bf(acc[i][1] * d);
            o.z = f2bf(acc[i][2] * d); o.w = f2bf(acc[i][3] * d);
            *(ushort4*)&G[(size_t)row * Ncols + c0 + tc] = o;
        }
    }
}

// ------- aggregation: out[i] = dinv[i]*(sum_nbr g[src] + g[i]) + b -------
// One wave per node; bf16 gather table, f32 accumulate.
// Main loop: exact UNR blocks, NO masks (pure adds). Tail: ONE masked
// UNR-wide batch (fully pipelined, single latency exposure).
template <int F, bool RELU, int UNR>
__global__ __launch_bounds__(256) void agg_kernel(
    const ushort* __restrict__ G, const int* __restrict__ rowptr,
    const int* __restrict__ colx, const float* __restrict__ dinv,
    const float* __restrict__ bias, float* __restrict__ Out, int N) {
    int wid = (int)((blockIdx.x * 256 + threadIdx.x) >> 6);
    int lane = threadIdx.x & 63;
    if (wid >= N) return;
    int s = rowptr[wid], e = rowptr[wid + 1];
    int nmain = (e - s) & ~(UNR - 1);
    int emain = s + nmain;

    if constexpr (F == 128) {
        const unsigned* gp = (const unsigned*)G;     // row = 64 dwords (2 bf16 each)
        unsigned su = gp[((size_t)wid << 6) + lane]; // self-loop term
        float ax = bf_lo(su), ay = bf_hi(su);
        float ax2 = 0.f, ay2 = 0.f;
        for (int j = s; j < emain; j += UNR) {       // exact, unmasked
            int c[UNR];
#pragma unroll
            for (int u = 0; u < UNR; ++u) c[u] = clampN(colx[j + u], N);
            unsigned v[UNR];
#pragma unroll
            for (int u = 0; u < UNR; ++u) v[u] = gp[((size_t)c[u] << 6) + lane];
#pragma unroll
            for (int u = 0; u < UNR; u += 2) {
                ax  += bf_lo(v[u]);     ay  += bf_hi(v[u]);
                ax2 += bf_lo(v[u + 1]); ay2 += bf_hi(v[u + 1]);
            }
        }
        if (emain < e) {                             // one masked batch
            int c[UNR];
            float w[UNR];
#pragma unroll
            for (int u = 0; u < UNR; ++u) {
                int jj = emain + u;
                bool m = jj < e;
                w[u] = m ? 1.f : 0.f;
                c[u] = clampN(colx[m ? jj : (e - 1)], N);
            }
            unsigned v[UNR];
#pragma unroll
            for (int u = 0; u < UNR; ++u) v[u] = gp[((size_t)c[u] << 6) + lane];
#pragma unroll
            for (int u = 0; u < UNR; u += 2) {
                ax  = fmaf(w[u],     bf_lo(v[u]),     ax);
                ay  = fmaf(w[u],     bf_hi(v[u]),     ay);
                ax2 = fmaf(w[u + 1], bf_lo(v[u + 1]), ax2);
                ay2 = fmaf(w[u + 1], bf_hi(v[u + 1]), ay2);
            }
        }
        ax += ax2; ay += ay2;
        float d = dinv[wid];
        float2 bv = *(const float2*)&bias[lane * 2];
        float ox = fmaf(d, ax, bv.x);
        float oy = fmaf(d, ay, bv.y);
        if (RELU) { ox = fmaxf(ox, 0.f); oy = fmaxf(oy, 0.f); }
        float2 o; o.x = ox; o.y = oy;
        *(float2*)&Out[(size_t)wid * F + lane * 2] = o;
    } else {  // F == 64
        const ushort* gp = G;                        // row = 64 bf16
        float acc = bf1(gp[((size_t)wid << 6) + lane]);  // self
        float acc2 = 0.f;
        for (int j = s; j < emain; j += UNR) {       // exact, unmasked
            int c[UNR];
#pragma unroll
            for (int u = 0; u < UNR; ++u) c[u] = clampN(colx[j + u], N);
            ushort v[UNR];
#pragma unroll
            for (int u = 0; u < UNR; ++u) v[u] = gp[((size_t)c[u] << 6) + lane];
#pragma unroll
            for (int u = 0; u < UNR; u += 2) {
                acc  += bf1(v[u]);
                acc2 += bf1(v[u + 1]);
            }
        }
        if (emain < e) {                             // one masked batch
            int c[UNR];
            float w[UNR];
#pragma unroll
            for (int u = 0; u < UNR; ++u) {
                int jj = emain + u;
                bool m = jj < e;
                w[u] = m ? 1.f : 0.f;
                c[u] = clampN(colx[m ? jj : (e - 1)], N);
            }
            ushort v[UNR];
#pragma unroll
            for (int u = 0; u < UNR; ++u) v[u] = gp[((size_t)c[u] << 6) + lane];
#pragma unroll
            for (int u = 0; u < UNR; u += 2) {
                acc  = fmaf(w[u],     bf1(v[u]),     acc);
                acc2 = fmaf(w[u + 1], bf1(v[u + 1]), acc2);
            }
        }
        acc += acc2;
        float o = fmaf(dinv[wid], acc, bias[lane]);
        if (RELU) o = fmaxf(o, 0.f);
        Out[(size_t)wid * F + lane] = o;
    }
}

extern "C" void kernel_launch(void* const* d_in, const int* in_sizes, int n_in,
                              void* d_out, int out_size, void* d_ws, size_t ws_size,
                              hipStream_t stream) {
    const float* x  = (const float*)d_in[0];
    const void*  ei = d_in[1];
    const float* w1 = (const float*)d_in[2];
    const float* b1 = (const float*)d_in[3];
    const float* w2 = (const float*)d_in[4];
    const float* b2 = (const float*)d_in[5];
    float* out = (float*)d_out;

    const int N  = in_sizes[0] / 128;   // 100000
    const int E  = in_sizes[1] / 2;     // 3200000
    const int M  = B * KB;              // cnt matrix cells
    const int NR = (N + B - 1) / B;     // nodes per bucket (<=128)

    char* p = (char*)d_ws;
    auto carve = [&](size_t bytes) {
        void* r = (void*)p;
        p += (bytes + 255) & ~(size_t)255;
        return r;
    };
    int*    cnt      = (int*)carve((size_t)M * 4);
    int*    base     = (int*)carve((size_t)M * 4);
    int*    partials = (int*)carve(1024 * 4);
    int*    flag     = (int*)carve(256);
    int*    rowptr   = (int*)carve((size_t)(N + 1) * 4);
    float*  dinv     = (float*)carve((size_t)N * 4);
    int*    colx     = (int*)carve((size_t)E * 4);
    ushort* g1       = (ushort*)carve((size_t)N * 128 * 2);  // bf16 gather table
    float*  a1       = (float*)carve((size_t)N * 128 * 4);
    ushort* g2       = g1;          // g1 dead after agg1; reuse
    int2*   buck     = (int2*)a1;   // buck (E*8=25.6MB) dead before agg1 writes a1

    const int EPB = (E + KB - 1) / KB;  // edges per K1/K3 block
    const int NBS = M / 256;            // scan blocks (1024)

    detect_i64<<<1, 64, 0, stream>>>((const int*)ei, flag);
    bucket_count<<<KB, 256, 0, stream>>>(ei, E, EPB, NR, flag, cnt, N);
    scan_partials<<<NBS, 256, 0, stream>>>(cnt, partials, M);
    scan_scan<<<1, 1024, 0, stream>>>(partials, NBS);
    scan_write<<<NBS, 256, 0, stream>>>(cnt, partials, base, M);
    bucket_scatter<<<KB, 256, 0, stream>>>(ei, E, EPB, NR, flag, base, buck, N);
    bucket_csr<<<B, 256, 0, stream>>>(buck, base, E, NR, dinv, rowptr, colx, N);

    dim3 grid1((N + 63) / 64, 2);
    gemm_scale<<<grid1, 256, 0, stream>>>(x, w1, dinv, g1, N, 128);
    agg_kernel<128, true, 16><<<(N + 3) / 4, 256, 0, stream>>>(g1, rowptr, colx, dinv, b1, a1, N);

    dim3 grid2((N + 63) / 64, 1);
    gemm_scale<<<grid2, 256, 0, stream>>>(a1, w2, dinv, g2, N, 64);
    agg_kernel<64, false, 16><<<(N + 3) / 4, 256, 0, stream>>>(g2, rowptr, colx, dinv, b2, out, N);
}

// Round 11
// 344.165 us; speedup vs baseline: 1.5242x; 1.0464x over previous
//
#include <hip/hip_runtime.h>
#include <hip/hip_fp16.h>

// 2-layer GCN: h1 = relu(Anorm @ (x@w1) + b1); out = Anorm @ (h1@w2) + b2
// Atomic-free bucket-sort CSR (R9). Gather tables in f16 (R11, was bf16).
// R10->R11 agg overhaul: (1) wave-uniform colx indices loaded ONCE per
// 16-batch (coalesced) and scalarized via readlane -> SGPR addressing;
// (2) packed f16 accumulate (v_pk_add_f16), f32 only in epilogue;
// (3) index clamp only in the masked tail. ~2 VALU/edge (was ~8).

constexpr int B = 1024;       // dst-range buckets
constexpr int KB = 256;       // blocks in K1/K3

// ---------------- edge dtype detect (int32 vs int64) ----------------
__global__ void detect_i64(const int* __restrict__ idx32, int* __restrict__ flag) {
    int v = idx32[2 * threadIdx.x + 1];
    unsigned long long b = __ballot(v != 0);
    if (threadIdx.x == 0) flag[0] = (b == 0ULL) ? 1 : 0;
}

__device__ __forceinline__ int load_idx(const void* edges, size_t i, int is64) {
    return is64 ? (int)((const long long*)edges)[i] : ((const int*)edges)[i];
}

__device__ __forceinline__ int clampN(int v, int N) {
    return ((unsigned)v < (unsigned)N) ? v : 0;
}

// ---- K1: per-block bucket histogram. cnt[bin*KB + blk] (bin-major). ----
__global__ __launch_bounds__(256) void bucket_count(
    const void* __restrict__ edges, int E, int EPB, int NR,
    const int* __restrict__ flag, int* __restrict__ cnt, int N) {
    __shared__ int hist[B];
    int t = threadIdx.x, b = blockIdx.x;
    for (int k = t; k < B; k += 256) hist[k] = 0;
    __syncthreads();
    int is64 = flag[0];
    int start = b * EPB, end = min(E, start + EPB);
    for (int j = start + t; j < end; j += 256) {
        int d = clampN(load_idx(edges, (size_t)E + j, is64), N);
        atomicAdd(&hist[d / NR], 1);
    }
    __syncthreads();
    for (int k = t; k < B; k += 256) cnt[(size_t)k * KB + b] = hist[k];
}

// ---------------- 3-kernel exclusive scan (M = B*KB elements) ----------------
__global__ void scan_partials(const int* __restrict__ in, int* __restrict__ partials, int M) {
    __shared__ int sm[256];
    int t = threadIdx.x, i = blockIdx.x * 256 + t;
    sm[t] = (i < M) ? in[i] : 0;
    __syncthreads();
    for (int off = 128; off > 0; off >>= 1) {
        if (t < off) sm[t] += sm[t + off];
        __syncthreads();
    }
    if (t == 0) partials[blockIdx.x] = sm[0];
}

__global__ void scan_scan(int* __restrict__ partials, int NB) {  // 1 block, 1024 thr
    __shared__ int sm[1024];
    int t = threadIdx.x;
    int v = (t < NB) ? partials[t] : 0;
    sm[t] = v; __syncthreads();
    for (int off = 1; off < 1024; off <<= 1) {
        int x = sm[t];
        int y = (t >= off) ? sm[t - off] : 0;
        __syncthreads();
        sm[t] = x + y;
        __syncthreads();
    }
    if (t < NB) partials[t] = (t == 0) ? 0 : sm[t - 1];  // exclusive
}

__global__ void scan_write(const int* __restrict__ in, const int* __restrict__ partials,
                           int* __restrict__ out, int M) {
    __shared__ int sm[256];
    int t = threadIdx.x, b = blockIdx.x, i = b * 256 + t;
    int v = (i < M) ? in[i] : 0;
    sm[t] = v; __syncthreads();
    for (int off = 1; off < 256; off <<= 1) {
        int x = sm[t];
        int y = (t >= off) ? sm[t - off] : 0;
        __syncthreads();
        sm[t] = x + y;
        __syncthreads();
    }
    if (i < M) out[i] = partials[b] + sm[t] - v;  // exclusive
}

// ---- K3: bucketed scatter. LDS cursors from base[bin*KB+blk]; buck=(src,dst). ----
__global__ __launch_bounds__(256) void bucket_scatter(
    const void* __restrict__ edges, int E, int EPB, int NR,
    const int* __restrict__ flag, const int* __restrict__ base,
    int2* __restrict__ buck, int N) {
    __shared__ int cur[B];
    int t = threadIdx.x, b = blockIdx.x;
    for (int k = t; k < B; k += 256) cur[k] = base[(size_t)k * KB + b];
    __syncthreads();
    int is64 = flag[0];
    int start = b * EPB, end = min(E, start + EPB);
    for (int j = start + t; j < end; j += 256) {
        int s = clampN(load_idx(edges, (size_t)j, is64), N);
        int d = clampN(load_idx(edges, (size_t)E + j, is64), N);
        int pos = atomicAdd(&cur[d / NR], 1);
        buck[pos] = make_int2(s, d);
    }
}

// ---- K4: per-bucket CSR. LDS count + scan; writes deg/dinv/rowptr/colx. ----
__global__ __launch_bounds__(256) void bucket_csr(
    const int2* __restrict__ buck, const int* __restrict__ base, int E, int NR,
    float* __restrict__ dinv, int* __restrict__ rowptr,
    int* __restrict__ colx, int N) {
    __shared__ int hist[128];  // NR <= 128
    __shared__ int cnt0[128];
    __shared__ int cur[128];
    int t = threadIdx.x, b = blockIdx.x;
    if (b == 0 && t == 0) rowptr[N] = E;
    int d0 = b * NR;
    if (d0 >= N) return;
    int nr = min(NR, N - d0);
    int segbase = base[(size_t)b * KB];
    int segend = (b == B - 1) ? E : base[(size_t)(b + 1) * KB];

    if (t < 128) hist[t] = 0;
    __syncthreads();
    for (int j = segbase + t; j < segend; j += 256)
        atomicAdd(&hist[buck[j].y - d0], 1);
    __syncthreads();
    if (t < 128) cnt0[t] = hist[t];
    __syncthreads();
    // inclusive scan over 128 (Hillis-Steele)
    for (int off = 1; off < 128; off <<= 1) {
        int v = 0;
        if (t < 128 && t >= off) v = hist[t - off];
        __syncthreads();
        if (t < 128) hist[t] += v;
        __syncthreads();
    }
    if (t < 128) {
        int ex = hist[t] - cnt0[t];  // exclusive
        cur[t] = ex;
        if (t < nr) {
            rowptr[d0 + t] = segbase + ex;
            dinv[d0 + t] = rsqrtf((float)(cnt0[t] + 1));  // +1 self-loop
        }
    }
    __syncthreads();
    for (int j = segbase + t; j < segend; j += 256) {
        int2 e = buck[j];
        int pos = segbase + atomicAdd(&cur[e.y - d0], 1);
        colx[pos] = e.x;
    }
}

// ------- GEMM: G = f16( dinv .* (X @ W) ), K=128 fixed -------
__global__ __launch_bounds__(256) void gemm_scale(
    const float* __restrict__ X, const float* __restrict__ W,
    const float* __restrict__ dinv, __half* __restrict__ G, int M, int Ncols) {
    constexpr int K = 128;
    __shared__ float xT[K][64];   // [k][row]
    __shared__ float ws[K][64];   // [k][col]
    const int t = threadIdx.x;
    const int m0 = blockIdx.x * 64;
    const int c0 = blockIdx.y * 64;

    {
        int cl = (t & 15) * 4;
        int k0 = t >> 4;
        for (int kk = 0; kk < K; kk += 16) {
            int k = k0 + kk;
            float4 wv = *(const float4*)&W[(size_t)k * Ncols + c0 + cl];
            *(float4*)&ws[k][cl] = wv;
        }
    }
    {
        int r = t & 63, cg = t >> 6;
        int row = m0 + r;
        bool valid = row < M;
        const float* xrow = &X[(size_t)(valid ? row : (M - 1)) * K];
        for (int cc = 0; cc < 8; ++cc) {
            int c = cg * 4 + cc * 16;
            float4 v;
            if (valid) v = *(const float4*)&xrow[c];
            else { v.x = v.y = v.z = v.w = 0.f; }
            xT[c + 0][r] = v.x; xT[c + 1][r] = v.y;
            xT[c + 2][r] = v.z; xT[c + 3][r] = v.w;
        }
    }
    __syncthreads();

    const int tc = (t & 15) * 4;
    const int tr = (t >> 4) * 4;
    float acc[4][4] = {};
#pragma unroll 8
    for (int k = 0; k < K; ++k) {
        float4 av = *(const float4*)&xT[k][tr];
        float4 bv = *(const float4*)&ws[k][tc];
        float a[4] = {av.x, av.y, av.z, av.w};
        float b[4] = {bv.x, bv.y, bv.z, bv.w};
#pragma unroll
        for (int i = 0; i < 4; ++i)
#pragma unroll
            for (int j = 0; j < 4; ++j)
                acc[i][j] = fmaf(a[i], b[j], acc[i][j]);
    }

#pragma unroll
    for (int i = 0; i < 4; ++i) {
        int row = m0 + tr + i;
        if (row < M) {
            float d = dinv[row];
            __half2 lo = __floats2half2_rn(acc[i][0] * d, acc[i][1] * d);
            __half2 hi = __floats2half2_rn(acc[i][2] * d, acc[i][3] * d);
            uint2 o;
            o.x = *(unsigned*)&lo;
            o.y = *(unsigned*)&hi;
            *(uint2*)&G[(size_t)row * Ncols + c0 + tc] = o;
        }
    }
}

// ------- aggregation: out[i] = dinv[i]*(sum_nbr g[src] + g[i]) + b -------
// One wave per node; f16 gather table, packed-f16 accumulate, f32 epilogue.
// colx indices: coalesced 16-wide load + readlane -> SGPR addressing.
// Main loop unmasked (colx valid by construction); masked+clamped tail.
template <int F, bool RELU, int UNR>
__global__ __launch_bounds__(256) void agg_kernel(
    const __half* __restrict__ G, const int* __restrict__ rowptr,
    const int* __restrict__ colx, const float* __restrict__ dinv,
    const float* __restrict__ bias, float* __restrict__ Out, int N) {
    static_assert(UNR == 16, "readlane batch hard-coded to 16");
    constexpr int LDW = F / 2;            // row stride in dwords (f16 pairs)
    constexpr int LSH = (F == 128) ? 6 : 5;
    int wid = (int)((blockIdx.x * 256 + threadIdx.x) >> 6);
    int lane = threadIdx.x & 63;
    if (wid >= N) return;
    int s = rowptr[wid], e = rowptr[wid + 1];
    int emain = s + ((e - s) & ~(UNR - 1));

    const unsigned* gp = (const unsigned*)G;
    const int dw = (F == 128) ? lane : (lane & 31);   // this lane's dword in row

    unsigned su = gp[((size_t)wid << LSH) + dw];      // self-loop term
    __half2 hacc = *(__half2*)&su;
    __half2 hacc2 = __floats2half2_rn(0.f, 0.f);

    for (int j = s; j < emain; j += UNR) {            // exact, unmasked
        int cl = colx[j + (lane & 15)];               // ONE coalesced load / batch
        unsigned v[UNR];
#pragma unroll
        for (int u = 0; u < UNR; ++u) {
            int cu = __builtin_amdgcn_readlane(cl, u);        // SGPR index
            v[u] = gp[((size_t)cu << LSH) + dw];
        }
#pragma unroll
        for (int u = 0; u < UNR; u += 2) {
            hacc  = __hadd2(hacc,  *(__half2*)&v[u]);
            hacc2 = __hadd2(hacc2, *(__half2*)&v[u + 1]);
        }
    }
    if (emain < e) {                                  // one masked batch
        int cl = clampN(colx[min(emain + (lane & 15), e - 1)], N);
        const __half2 one2 = __floats2half2_rn(1.f, 1.f);
        const __half2 zero2 = __floats2half2_rn(0.f, 0.f);
        unsigned v[UNR];
        __half2 w[UNR];
#pragma unroll
        for (int u = 0; u < UNR; ++u) {
            int cu = __builtin_amdgcn_readlane(cl, u);
            w[u] = (emain + u < e) ? one2 : zero2;
            v[u] = gp[((size_t)cu << LSH) + dw];
        }
#pragma unroll
        for (int u = 0; u < UNR; u += 2) {
            hacc  = __hfma2(w[u],     *(__half2*)&v[u],     hacc);
            hacc2 = __hfma2(w[u + 1], *(__half2*)&v[u + 1], hacc2);
        }
    }

    float2 f1 = __half22float2(hacc);
    float2 f2 = __half22float2(hacc2);
    float ax = f1.x + f2.x, ay = f1.y + f2.y;
    float d = dinv[wid];

    if constexpr (F == 128) {
        float2 bv = *(const float2*)&bias[lane * 2];
        float ox = fmaf(d, ax, bv.x);
        float oy = fmaf(d, ay, bv.y);
        if (RELU) { ox = fmaxf(ox, 0.f); oy = fmaxf(oy, 0.f); }
        float2 o; o.x = ox; o.y = oy;
        *(float2*)&Out[(size_t)wid * F + lane * 2] = o;
    } else {
        if (lane < 32) {
            float2 bv = *(const float2*)&bias[lane * 2];
            float ox = fmaf(d, ax, bv.x);
            float oy = fmaf(d, ay, bv.y);
            if (RELU) { ox = fmaxf(ox, 0.f); oy = fmaxf(oy, 0.f); }
            float2 o; o.x = ox; o.y = oy;
            *(float2*)&Out[(size_t)wid * F + lane * 2] = o;
        }
    }
}

extern "C" void kernel_launch(void* const* d_in, const int* in_sizes, int n_in,
                              void* d_out, int out_size, void* d_ws, size_t ws_size,
                              hipStream_t stream) {
    const float* x  = (const float*)d_in[0];
    const void*  ei = d_in[1];
    const float* w1 = (const float*)d_in[2];
    const float* b1 = (const float*)d_in[3];
    const float* w2 = (const float*)d_in[4];
    const float* b2 = (const float*)d_in[5];
    float* out = (float*)d_out;

    const int N  = in_sizes[0] / 128;   // 100000
    const int E  = in_sizes[1] / 2;     // 3200000
    const int M  = B * KB;              // cnt matrix cells
    const int NR = (N + B - 1) / B;     // nodes per bucket (<=128)

    char* p = (char*)d_ws;
    auto carve = [&](size_t bytes) {
        void* r = (void*)p;
        p += (bytes + 255) & ~(size_t)255;
        return r;
    };
    int*    cnt      = (int*)carve((size_t)M * 4);
    int*    base     = (int*)carve((size_t)M * 4);
    int*    partials = (int*)carve(1024 * 4);
    int*    flag     = (int*)carve(256);
    int*    rowptr   = (int*)carve((size_t)(N + 1) * 4);
    float*  dinv     = (float*)carve((size_t)N * 4);
    int*    colx     = (int*)carve((size_t)E * 4);
    __half* g1       = (__half*)carve((size_t)N * 128 * 2);  // f16 gather table
    float*  a1       = (float*)carve((size_t)N * 128 * 4);
    __half* g2       = g1;          // g1 dead after agg1; reuse
    int2*   buck     = (int2*)a1;   // buck dead before agg1 writes a1

    const int EPB = (E + KB - 1) / KB;  // edges per K1/K3 block
    const int NBS = M / 256;            // scan blocks (1024)

    detect_i64<<<1, 64, 0, stream>>>((const int*)ei, flag);
    bucket_count<<<KB, 256, 0, stream>>>(ei, E, EPB, NR, flag, cnt, N);
    scan_partials<<<NBS, 256, 0, stream>>>(cnt, partials, M);
    scan_scan<<<1, 1024, 0, stream>>>(partials, NBS);
    scan_write<<<NBS, 256, 0, stream>>>(cnt, partials, base, M);
    bucket_scatter<<<KB, 256, 0, stream>>>(ei, E, EPB, NR, flag, base, buck, N);
    bucket_csr<<<B, 256, 0, stream>>>(buck, base, E, NR, dinv, rowptr, colx, N);

    dim3 grid1((N + 63) / 64, 2);
    gemm_scale<<<grid1, 256, 0, stream>>>(x, w1, dinv, g1, N, 128);
    agg_kernel<128, true, 16><<<(N + 3) / 4, 256, 0, stream>>>(g1, rowptr, colx, dinv, b1, a1, N);

    dim3 grid2((N + 63) / 64, 1);
    gemm_scale<<<grid2, 256, 0, stream>>>(a1, w2, dinv, g2, N, 64);
    agg_kernel<64, false, 16><<<(N + 3) / 4, 256, 0, stream>>>(g2, rowptr, colx, dinv, b2, out, N);
}

// Round 12
// 342.801 us; speedup vs baseline: 1.5303x; 1.0040x over previous
//
#include <hip/hip_runtime.h>
#include <hip/hip_fp16.h>
#include <type_traits>

// 2-layer GCN: h1 = relu(Anorm @ (x@w1) + b1); out = Anorm @ (h1@w2) + b2
// Atomic-free bucket-sort CSR; f16 gather tables; packed-f16 accumulate.
// R11->R12 (all traffic cuts; ~3.9TB/s TCC rate is the measured ceiling):
//  (1) agg1 split into two half-row passes (128B line per row per pass ->
//      working set 25.6->12.8MB, fewer L2 capacity misses); 2 edges/iter
//      via half-waves + shfl_xor(32) reduce.
//  (2) a1 stored f16 (agg1 WRITE and gemm2 FETCH halve).
//  (3) bucket records packed to int32 (dlocal<<17|src).

constexpr int B = 1024;       // dst-range buckets
constexpr int KB = 256;       // blocks in K1/K3

// ---------------- edge dtype detect (int32 vs int64) ----------------
__global__ void detect_i64(const int* __restrict__ idx32, int* __restrict__ flag) {
    int v = idx32[2 * threadIdx.x + 1];
    unsigned long long b = __ballot(v != 0);
    if (threadIdx.x == 0) flag[0] = (b == 0ULL) ? 1 : 0;
}

__device__ __forceinline__ int load_idx(const void* edges, size_t i, int is64) {
    return is64 ? (int)((const long long*)edges)[i] : ((const int*)edges)[i];
}

__device__ __forceinline__ int clampN(int v, int N) {
    return ((unsigned)v < (unsigned)N) ? v : 0;
}

// ---- K1: per-block bucket histogram. cnt[bin*KB + blk] (bin-major). ----
__global__ __launch_bounds__(256) void bucket_count(
    const void* __restrict__ edges, int E, int EPB, int NR,
    const int* __restrict__ flag, int* __restrict__ cnt, int N) {
    __shared__ int hist[B];
    int t = threadIdx.x, b = blockIdx.x;
    for (int k = t; k < B; k += 256) hist[k] = 0;
    __syncthreads();
    int is64 = flag[0];
    int start = b * EPB, end = min(E, start + EPB);
    for (int j = start + t; j < end; j += 256) {
        int d = clampN(load_idx(edges, (size_t)E + j, is64), N);
        atomicAdd(&hist[d / NR], 1);
    }
    __syncthreads();
    for (int k = t; k < B; k += 256) cnt[(size_t)k * KB + b] = hist[k];
}

// ---------------- 3-kernel exclusive scan (M = B*KB elements) ----------------
__global__ void scan_partials(const int* __restrict__ in, int* __restrict__ partials, int M) {
    __shared__ int sm[256];
    int t = threadIdx.x, i = blockIdx.x * 256 + t;
    sm[t] = (i < M) ? in[i] : 0;
    __syncthreads();
    for (int off = 128; off > 0; off >>= 1) {
        if (t < off) sm[t] += sm[t + off];
        __syncthreads();
    }
    if (t == 0) partials[blockIdx.x] = sm[0];
}

__global__ void scan_scan(int* __restrict__ partials, int NB) {  // 1 block, 1024 thr
    __shared__ int sm[1024];
    int t = threadIdx.x;
    int v = (t < NB) ? partials[t] : 0;
    sm[t] = v; __syncthreads();
    for (int off = 1; off < 1024; off <<= 1) {
        int x = sm[t];
        int y = (t >= off) ? sm[t - off] : 0;
        __syncthreads();
        sm[t] = x + y;
        __syncthreads();
    }
    if (t < NB) partials[t] = (t == 0) ? 0 : sm[t - 1];  // exclusive
}

__global__ void scan_write(const int* __restrict__ in, const int* __restrict__ partials,
                           int* __restrict__ out, int M) {
    __shared__ int sm[256];
    int t = threadIdx.x, b = blockIdx.x, i = b * 256 + t;
    int v = (i < M) ? in[i] : 0;
    sm[t] = v; __syncthreads();
    for (int off = 1; off < 256; off <<= 1) {
        int x = sm[t];
        int y = (t >= off) ? sm[t - off] : 0;
        __syncthreads();
        sm[t] = x + y;
        __syncthreads();
    }
    if (i < M) out[i] = partials[b] + sm[t] - v;  // exclusive
}

// ---- K3: bucketed scatter. LDS cursors; packed record (dlocal<<17 | src). ----
__global__ __launch_bounds__(256) void bucket_scatter(
    const void* __restrict__ edges, int E, int EPB, int NR,
    const int* __restrict__ flag, const int* __restrict__ base,
    int* __restrict__ buck, int N) {
    __shared__ int cur[B];
    int t = threadIdx.x, b = blockIdx.x;
    for (int k = t; k < B; k += 256) cur[k] = base[(size_t)k * KB + b];
    __syncthreads();
    int is64 = flag[0];
    int start = b * EPB, end = min(E, start + EPB);
    for (int j = start + t; j < end; j += 256) {
        int s = clampN(load_idx(edges, (size_t)j, is64), N);
        int d = clampN(load_idx(edges, (size_t)E + j, is64), N);
        int bin = d / NR;
        int dl = d - bin * NR;
        int pos = atomicAdd(&cur[bin], 1);
        buck[pos] = (dl << 17) | s;
    }
}

// ---- K4: per-bucket CSR. LDS count + scan; writes dinv/rowptr/colx. ----
__global__ __launch_bounds__(256) void bucket_csr(
    const int* __restrict__ buck, const int* __restrict__ base, int E, int NR,
    float* __restrict__ dinv, int* __restrict__ rowptr,
    int* __restrict__ colx, int N) {
    __shared__ int hist[128];  // NR <= 128
    __shared__ int cnt0[128];
    __shared__ int cur[128];
    int t = threadIdx.x, b = blockIdx.x;
    if (b == 0 && t == 0) rowptr[N] = E;
    int d0 = b * NR;
    if (d0 >= N) return;
    int nr = min(NR, N - d0);
    int segbase = base[(size_t)b * KB];
    int segend = (b == B - 1) ? E : base[(size_t)(b + 1) * KB];

    if (t < 128) hist[t] = 0;
    __syncthreads();
    for (int j = segbase + t; j < segend; j += 256)
        atomicAdd(&hist[buck[j] >> 17], 1);
    __syncthreads();
    if (t < 128) cnt0[t] = hist[t];
    __syncthreads();
    for (int off = 1; off < 128; off <<= 1) {  // inclusive scan
        int v = 0;
        if (t < 128 && t >= off) v = hist[t - off];
        __syncthreads();
        if (t < 128) hist[t] += v;
        __syncthreads();
    }
    if (t < 128) {
        int ex = hist[t] - cnt0[t];  // exclusive
        cur[t] = ex;
        if (t < nr) {
            rowptr[d0 + t] = segbase + ex;
            dinv[d0 + t] = rsqrtf((float)(cnt0[t] + 1));  // +1 self-loop
        }
    }
    __syncthreads();
    for (int j = segbase + t; j < segend; j += 256) {
        int v = buck[j];
        int pos = segbase + atomicAdd(&cur[v >> 17], 1);
        colx[pos] = v & 0x1FFFF;
    }
}

// ------- GEMM: G = f16( dinv .* (X @ W) ), K=128 fixed; X f32 or f16 -------
template <typename XT>
__global__ __launch_bounds__(256) void gemm_scale(
    const XT* __restrict__ X, const float* __restrict__ W,
    const float* __restrict__ dinv, __half* __restrict__ G, int M, int Ncols) {
    constexpr int K = 128;
    __shared__ float xT[K][64];   // [k][row]
    __shared__ float ws[K][64];   // [k][col]
    const int t = threadIdx.x;
    const int m0 = blockIdx.x * 64;
    const int c0 = blockIdx.y * 64;

    {
        int cl = (t & 15) * 4;
        int k0 = t >> 4;
        for (int kk = 0; kk < K; kk += 16) {
            int k = k0 + kk;
            float4 wv = *(const float4*)&W[(size_t)k * Ncols + c0 + cl];
            *(float4*)&ws[k][cl] = wv;
        }
    }
    {
        int r = t & 63, cg = t >> 6;
        int row = m0 + r;
        bool valid = row < M;
        const XT* xrow = &X[(size_t)(valid ? row : (M - 1)) * K];
        for (int cc = 0; cc < 8; ++cc) {
            int c = cg * 4 + cc * 16;
            float4 v;
            if (valid) {
                if constexpr (std::is_same<XT, __half>::value) {
                    const __half2* hp = (const __half2*)&xrow[c];
                    float2 f0 = __half22float2(hp[0]);
                    float2 f1 = __half22float2(hp[1]);
                    v.x = f0.x; v.y = f0.y; v.z = f1.x; v.w = f1.y;
                } else {
                    v = *(const float4*)&xrow[c];
                }
            } else { v.x = v.y = v.z = v.w = 0.f; }
            xT[c + 0][r] = v.x; xT[c + 1][r] = v.y;
            xT[c + 2][r] = v.z; xT[c + 3][r] = v.w;
        }
    }
    __syncthreads();

    const int tc = (t & 15) * 4;
    const int tr = (t >> 4) * 4;
    float acc[4][4] = {};
#pragma unroll 8
    for (int k = 0; k < K; ++k) {
        float4 av = *(const float4*)&xT[k][tr];
        float4 bv = *(const float4*)&ws[k][tc];
        float a[4] = {av.x, av.y, av.z, av.w};
        float b[4] = {bv.x, bv.y, bv.z, bv.w};
#pragma unroll
        for (int i = 0; i < 4; ++i)
#pragma unroll
            for (int j = 0; j < 4; ++j)
                acc[i][j] = fmaf(a[i], b[j], acc[i][j]);
    }

#pragma unroll
    for (int i = 0; i < 4; ++i) {
        int row = m0 + tr + i;
        if (row < M) {
            float d = dinv[row];
            __half2 lo = __floats2half2_rn(acc[i][0] * d, acc[i][1] * d);
            __half2 hi = __floats2half2_rn(acc[i][2] * d, acc[i][3] * d);
            uint2 o;
            o.x = *(unsigned*)&lo;
            o.y = *(unsigned*)&hi;
            *(uint2*)&G[(size_t)row * Ncols + c0 + tc] = o;
        }
    }
}

// ------- agg1 half-row pass: features [p*64, p*64+64), F=128 table -------
// One wave per node; lanes 0-31 = edge u, lanes 32-63 = edge u+1 (pairs);
// each half-wave covers the 32-dword (128B) half-row -> one L2 line/row.
// Cross-half shfl_xor(32) reduce; lanes<32 write f16 output (bias+relu f32).
__global__ __launch_bounds__(256) void agg_split(
    const __half* __restrict__ G, const int* __restrict__ rowptr,
    const int* __restrict__ colx, const float* __restrict__ dinv,
    const float* __restrict__ bias, __half* __restrict__ Out, int N, int p) {
    constexpr int UNR = 16;
    int wid = (int)((blockIdx.x * 256 + threadIdx.x) >> 6);
    int lane = threadIdx.x & 63;
    if (wid >= N) return;
    int s = rowptr[wid], e = rowptr[wid + 1];
    int emain = s + ((e - s) & ~(UNR - 1));

    const unsigned* gp = (const unsigned*)G;       // row = 64 dwords
    int dw = p * 32 + (lane & 31);
    int half = lane >> 5;                          // 0 or 1

    __half2 z = __floats2half2_rn(0.f, 0.f);
    unsigned su = gp[(size_t)wid * 64 + dw];       // self term (count once)
    __half2 hacc = half ? z : *(__half2*)&su;
    __half2 hacc2 = z;

    for (int j = s; j < emain; j += UNR) {         // exact, unmasked
        int cl = colx[j + (lane & 15)];            // one coalesced load/batch
        unsigned v[UNR / 2];
#pragma unroll
        for (int u = 0; u < UNR; u += 2) {
            int c0 = __builtin_amdgcn_readlane(cl, u);
            int c1 = __builtin_amdgcn_readlane(cl, u + 1);
            int cu = half ? c1 : c0;
            v[u / 2] = gp[(size_t)cu * 64 + dw];
        }
#pragma unroll
        for (int u = 0; u < UNR; u += 4) {
            hacc  = __hadd2(hacc,  *(__half2*)&v[u / 2]);
            hacc2 = __hadd2(hacc2, *(__half2*)&v[u / 2 + 1]);
        }
    }
    if (emain < e) {                               // one masked batch
        int cl = clampN(colx[min(emain + (lane & 15), e - 1)], N);
        const __half2 one2 = __floats2half2_rn(1.f, 1.f);
#pragma unroll
        for (int u = 0; u < UNR; u += 2) {
            int c0 = __builtin_amdgcn_readlane(cl, u);
            int c1 = __builtin_amdgcn_readlane(cl, u + 1);
            int cu = half ? c1 : c0;
            unsigned vv = gp[(size_t)cu * 64 + dw];
            int jj = emain + u + half;
            __half2 w = (jj < e) ? one2 : z;
            hacc = __hfma2(w, *(__half2*)&vv, hacc);
        }
    }

    hacc = __hadd2(hacc, hacc2);
    int bits = *(int*)&hacc;
    int other = __shfl_xor(bits, 32, 64);          // cross-half partial
    __half2 ho = *(__half2*)&other;
    float2 f1 = __half22float2(hacc);
    float2 f2 = __half22float2(ho);
    float ax = f1.x + f2.x, ay = f1.y + f2.y;

    if (half == 0) {
        float d = dinv[wid];
        float2 bv = *(const float2*)&bias[dw * 2];
        float ox = fmaf(d, ax, bv.x);
        float oy = fmaf(d, ay, bv.y);
        ox = fmaxf(ox, 0.f); oy = fmaxf(oy, 0.f);  // relu (layer 1)
        __half2 h = __floats2half2_rn(ox, oy);
        ((unsigned*)Out)[(size_t)wid * 64 + dw] = *(unsigned*)&h;
    }
}

// ------- agg layer-2 (F=64): f16 table, packed accumulate, f32 out -------
template <int UNR>
__global__ __launch_bounds__(256) void agg2_kernel(
    const __half* __restrict__ G, const int* __restrict__ rowptr,
    const int* __restrict__ colx, const float* __restrict__ dinv,
    const float* __restrict__ bias, float* __restrict__ Out, int N) {
    static_assert(UNR == 16, "readlane batch hard-coded to 16");
    int wid = (int)((blockIdx.x * 256 + threadIdx.x) >> 6);
    int lane = threadIdx.x & 63;
    if (wid >= N) return;
    int s = rowptr[wid], e = rowptr[wid + 1];
    int emain = s + ((e - s) & ~(UNR - 1));

    const unsigned* gp = (const unsigned*)G;       // row = 32 dwords
    const int dw = lane & 31;

    unsigned su = gp[((size_t)wid << 5) + dw];     // self term
    __half2 hacc = *(__half2*)&su;
    __half2 hacc2 = __floats2half2_rn(0.f, 0.f);

    for (int j = s; j < emain; j += UNR) {
        int cl = colx[j + (lane & 15)];
        unsigned v[UNR];
#pragma unroll
        for (int u = 0; u < UNR; ++u) {
            int cu = __builtin_amdgcn_readlane(cl, u);
            v[u] = gp[((size_t)cu << 5) + dw];
        }
#pragma unroll
        for (int u = 0; u < UNR; u += 2) {
            hacc  = __hadd2(hacc,  *(__half2*)&v[u]);
            hacc2 = __hadd2(hacc2, *(__half2*)&v[u + 1]);
        }
    }
    if (emain < e) {
        int cl = clampN(colx[min(emain + (lane & 15), e - 1)], N);
        const __half2 one2 = __floats2half2_rn(1.f, 1.f);
        const __half2 zero2 = __floats2half2_rn(0.f, 0.f);
#pragma unroll
        for (int u = 0; u < UNR; ++u) {
            int cu = __builtin_amdgcn_readlane(cl, u);
            unsigned vv = gp[((size_t)cu << 5) + dw];
            __half2 w = (emain + u < e) ? one2 : zero2;
            hacc = __hfma2(w, *(__half2*)&vv, hacc);
        }
    }

    float2 f1 = __half22float2(hacc);
    float2 f2 = __half22float2(hacc2);
    float ax = f1.x + f2.x, ay = f1.y + f2.y;
    float d = dinv[wid];
    if (lane < 32) {
        float2 bv = *(const float2*)&bias[dw * 2];
        float2 o;
        o.x = fmaf(d, ax, bv.x);
        o.y = fmaf(d, ay, bv.y);
        *(float2*)&Out[(size_t)wid * 64 + dw * 2] = o;
    }
}

extern "C" void kernel_launch(void* const* d_in, const int* in_sizes, int n_in,
                              void* d_out, int out_size, void* d_ws, size_t ws_size,
                              hipStream_t stream) {
    const float* x  = (const float*)d_in[0];
    const void*  ei = d_in[1];
    const float* w1 = (const float*)d_in[2];
    const float* b1 = (const float*)d_in[3];
    const float* w2 = (const float*)d_in[4];
    const float* b2 = (const float*)d_in[5];
    float* out = (float*)d_out;

    const int N  = in_sizes[0] / 128;   // 100000
    const int E  = in_sizes[1] / 2;     // 3200000
    const int M  = B * KB;              // cnt matrix cells
    const int NR = (N + B - 1) / B;     // nodes per bucket (<=128)

    char* p = (char*)d_ws;
    auto carve = [&](size_t bytes) {
        void* r = (void*)p;
        p += (bytes + 255) & ~(size_t)255;
        return r;
    };
    int*    cnt      = (int*)carve((size_t)M * 4);
    int*    base     = (int*)carve((size_t)M * 4);
    int*    partials = (int*)carve(1024 * 4);
    int*    flag     = (int*)carve(256);
    int*    rowptr   = (int*)carve((size_t)(N + 1) * 4);
    float*  dinv     = (float*)carve((size_t)N * 4);
    int*    colx     = (int*)carve((size_t)E * 4);
    __half* g1       = (__half*)carve((size_t)N * 128 * 2);  // f16 gather table
    __half* a1       = (__half*)carve((size_t)N * 128 * 2);  // f16 h1
    __half* g2       = g1;          // g1 dead after agg1; reuse
    int*    buck     = (int*)a1;    // packed records dead before agg1 writes a1

    const int EPB = (E + KB - 1) / KB;  // edges per K1/K3 block
    const int NBS = M / 256;            // scan blocks (1024)

    detect_i64<<<1, 64, 0, stream>>>((const int*)ei, flag);
    bucket_count<<<KB, 256, 0, stream>>>(ei, E, EPB, NR, flag, cnt, N);
    scan_partials<<<NBS, 256, 0, stream>>>(cnt, partials, M);
    scan_scan<<<1, 1024, 0, stream>>>(partials, NBS);
    scan_write<<<NBS, 256, 0, stream>>>(cnt, partials, base, M);
    bucket_scatter<<<KB, 256, 0, stream>>>(ei, E, EPB, NR, flag, base, buck, N);
    bucket_csr<<<B, 256, 0, stream>>>(buck, base, E, NR, dinv, rowptr, colx, N);

    // layer 1
    dim3 grid1((N + 63) / 64, 2);
    gemm_scale<float><<<grid1, 256, 0, stream>>>(x, w1, dinv, g1, N, 128);
    const int aggb = (N + 3) / 4;
    agg_split<<<aggb, 256, 0, stream>>>(g1, rowptr, colx, dinv, b1, a1, N, 0);
    agg_split<<<aggb, 256, 0, stream>>>(g1, rowptr, colx, dinv, b1, a1, N, 1);

    // layer 2
    dim3 grid2((N + 63) / 64, 1);
    gemm_scale<__half><<<grid2, 256, 0, stream>>>(a1, w2, dinv, g2, N, 64);
    agg2_kernel<16><<<aggb, 256, 0, stream>>>(g2, rowptr, colx, dinv, b2, out, N);
}

// Round 13
// 304.311 us; speedup vs baseline: 1.7239x; 1.1265x over previous
//
#include <hip/hip_runtime.h>
#include <hip/hip_fp16.h>
#include <type_traits>

// 2-layer GCN: h1 = relu(Anorm @ (x@w1) + b1); out = Anorm @ (h1@w2) + b2
// Atomic-free bucket-sort CSR; f16 gather tables; packed-f16 agg accumulate.
// R12->R13: GEMMs moved to MFMA (v_mfma_f32_16x16x32_f16, f32 accumulate).
// 64x64 tile, BK=128, 4 waves; LDS tiles padded +8 f16 (bank-conflict-free
// ds_read_b128). gemm was 70us VALU-f32 at 18.7% occupancy -- matmul-shaped
// work belongs on matrix cores (no fp32 MFMA on CDNA4 -> f16 inputs).

constexpr int B = 1024;       // dst-range buckets
constexpr int KB = 256;       // blocks in K1/K3

using half8 = __attribute__((ext_vector_type(8))) _Float16;
using f32x4 = __attribute__((ext_vector_type(4))) float;

// ---------------- edge dtype detect (int32 vs int64) ----------------
__global__ void detect_i64(const int* __restrict__ idx32, int* __restrict__ flag) {
    int v = idx32[2 * threadIdx.x + 1];
    unsigned long long b = __ballot(v != 0);
    if (threadIdx.x == 0) flag[0] = (b == 0ULL) ? 1 : 0;
}

__device__ __forceinline__ int load_idx(const void* edges, size_t i, int is64) {
    return is64 ? (int)((const long long*)edges)[i] : ((const int*)edges)[i];
}

__device__ __forceinline__ int clampN(int v, int N) {
    return ((unsigned)v < (unsigned)N) ? v : 0;
}

// ---- K1: per-block bucket histogram. cnt[bin*KB + blk] (bin-major). ----
__global__ __launch_bounds__(256) void bucket_count(
    const void* __restrict__ edges, int E, int EPB, int NR,
    const int* __restrict__ flag, int* __restrict__ cnt, int N) {
    __shared__ int hist[B];
    int t = threadIdx.x, b = blockIdx.x;
    for (int k = t; k < B; k += 256) hist[k] = 0;
    __syncthreads();
    int is64 = flag[0];
    int start = b * EPB, end = min(E, start + EPB);
    for (int j = start + t; j < end; j += 256) {
        int d = clampN(load_idx(edges, (size_t)E + j, is64), N);
        atomicAdd(&hist[d / NR], 1);
    }
    __syncthreads();
    for (int k = t; k < B; k += 256) cnt[(size_t)k * KB + b] = hist[k];
}

// ---------------- 3-kernel exclusive scan (M = B*KB elements) ----------------
__global__ void scan_partials(const int* __restrict__ in, int* __restrict__ partials, int M) {
    __shared__ int sm[256];
    int t = threadIdx.x, i = blockIdx.x * 256 + t;
    sm[t] = (i < M) ? in[i] : 0;
    __syncthreads();
    for (int off = 128; off > 0; off >>= 1) {
        if (t < off) sm[t] += sm[t + off];
        __syncthreads();
    }
    if (t == 0) partials[blockIdx.x] = sm[0];
}

__global__ void scan_scan(int* __restrict__ partials, int NB) {  // 1 block, 1024 thr
    __shared__ int sm[1024];
    int t = threadIdx.x;
    int v = (t < NB) ? partials[t] : 0;
    sm[t] = v; __syncthreads();
    for (int off = 1; off < 1024; off <<= 1) {
        int x = sm[t];
        int y = (t >= off) ? sm[t - off] : 0;
        __syncthreads();
        sm[t] = x + y;
        __syncthreads();
    }
    if (t < NB) partials[t] = (t == 0) ? 0 : sm[t - 1];  // exclusive
}

__global__ void scan_write(const int* __restrict__ in, const int* __restrict__ partials,
                           int* __restrict__ out, int M) {
    __shared__ int sm[256];
    int t = threadIdx.x, b = blockIdx.x, i = b * 256 + t;
    int v = (i < M) ? in[i] : 0;
    sm[t] = v; __syncthreads();
    for (int off = 1; off < 256; off <<= 1) {
        int x = sm[t];
        int y = (t >= off) ? sm[t - off] : 0;
        __syncthreads();
        sm[t] = x + y;
        __syncthreads();
    }
    if (i < M) out[i] = partials[b] + sm[t] - v;  // exclusive
}

// ---- K3: bucketed scatter. LDS cursors; packed record (dlocal<<17 | src). ----
__global__ __launch_bounds__(256) void bucket_scatter(
    const void* __restrict__ edges, int E, int EPB, int NR,
    const int* __restrict__ flag, const int* __restrict__ base,
    int* __restrict__ buck, int N) {
    __shared__ int cur[B];
    int t = threadIdx.x, b = blockIdx.x;
    for (int k = t; k < B; k += 256) cur[k] = base[(size_t)k * KB + b];
    __syncthreads();
    int is64 = flag[0];
    int start = b * EPB, end = min(E, start + EPB);
    for (int j = start + t; j < end; j += 256) {
        int s = clampN(load_idx(edges, (size_t)j, is64), N);
        int d = clampN(load_idx(edges, (size_t)E + j, is64), N);
        int bin = d / NR;
        int dl = d - bin * NR;
        int pos = atomicAdd(&cur[bin], 1);
        buck[pos] = (dl << 17) | s;
    }
}

// ---- K4: per-bucket CSR. LDS count + scan; writes dinv/rowptr/colx. ----
__global__ __launch_bounds__(256) void bucket_csr(
    const int* __restrict__ buck, const int* __restrict__ base, int E, int NR,
    float* __restrict__ dinv, int* __restrict__ rowptr,
    int* __restrict__ colx, int N) {
    __shared__ int hist[128];  // NR <= 128
    __shared__ int cnt0[128];
    __shared__ int cur[128];
    int t = threadIdx.x, b = blockIdx.x;
    if (b == 0 && t == 0) rowptr[N] = E;
    int d0 = b * NR;
    if (d0 >= N) return;
    int nr = min(NR, N - d0);
    int segbase = base[(size_t)b * KB];
    int segend = (b == B - 1) ? E : base[(size_t)(b + 1) * KB];

    if (t < 128) hist[t] = 0;
    __syncthreads();
    for (int j = segbase + t; j < segend; j += 256)
        atomicAdd(&hist[buck[j] >> 17], 1);
    __syncthreads();
    if (t < 128) cnt0[t] = hist[t];
    __syncthreads();
    for (int off = 1; off < 128; off <<= 1) {  // inclusive scan
        int v = 0;
        if (t < 128 && t >= off) v = hist[t - off];
        __syncthreads();
        if (t < 128) hist[t] += v;
        __syncthreads();
    }
    if (t < 128) {
        int ex = hist[t] - cnt0[t];  // exclusive
        cur[t] = ex;
        if (t < nr) {
            rowptr[d0 + t] = segbase + ex;
            dinv[d0 + t] = rsqrtf((float)(cnt0[t] + 1));  // +1 self-loop
        }
    }
    __syncthreads();
    for (int j = segbase + t; j < segend; j += 256) {
        int v = buck[j];
        int pos = segbase + atomicAdd(&cur[v >> 17], 1);
        colx[pos] = v & 0x1FFFF;
    }
}

// ------- MFMA GEMM: G = f16( dinv .* (X @ W) ), K=128; X f32 or f16 -------
// 64x64 tile, 4 waves; LDS [64][128+8] f16 for A (row-major k) and B^T
// (col-major k). Fragments: A row=lane&15, k=(lane>>4)*8+i; B col=lane&15,
// same k chunk; D col=lane&15, row=(lane>>4)*4+i (guide-verified mapping).
template <typename XT>
__global__ __launch_bounds__(256) void gemm_mfma(
    const XT* __restrict__ X, const float* __restrict__ W,
    const float* __restrict__ dinv, __half* __restrict__ G, int M, int Ncols) {
    constexpr int BK = 128;
    constexpr int LDP = BK + 8;           // padded stride (f16) -> 272B, 16B-aligned
    __shared__ _Float16 xA[64][LDP];      // [row][k]
    __shared__ _Float16 wB[64][LDP];      // [col][k]
    const int t = threadIdx.x;
    const int m0 = blockIdx.x * 64;
    const int c0 = blockIdx.y * 64;

    // stage A: 64 rows x 128 k
    {
        int r = t & 63, kg = t >> 6;      // kg in [0,4): k range [kg*32, kg*32+32)
        int row = m0 + r; if (row >= M) row = M - 1;
        const XT* xr = &X[(size_t)row * BK + kg * 32];
        if constexpr (std::is_same<XT, __half>::value) {
            const uint4* src = (const uint4*)xr;          // 32 f16 = 4 x 16B
            uint4* dst = (uint4*)&xA[r][kg * 32];
#pragma unroll
            for (int q = 0; q < 4; ++q) dst[q] = src[q];
        } else {
#pragma unroll
            for (int c = 0; c < 32; c += 8) {
                float4 a = *(const float4*)&xr[c];
                float4 b = *(const float4*)&xr[c + 4];
                half8 h;
                h[0] = (_Float16)a.x; h[1] = (_Float16)a.y;
                h[2] = (_Float16)a.z; h[3] = (_Float16)a.w;
                h[4] = (_Float16)b.x; h[5] = (_Float16)b.y;
                h[6] = (_Float16)b.z; h[7] = (_Float16)b.w;
                *(half8*)&xA[r][kg * 32 + c] = h;
            }
        }
    }
    // stage B transposed: W[k][c0+c] (f32) -> wB[c][k]
    {
        int cg = t & 15, k0 = t >> 4;     // k0 in [0,16)
#pragma unroll
        for (int kk = 0; kk < 8; ++kk) {
            int k = k0 + kk * 16;
            float4 wv = *(const float4*)&W[(size_t)k * Ncols + c0 + cg * 4];
            wB[cg * 4 + 0][k] = (_Float16)wv.x;
            wB[cg * 4 + 1][k] = (_Float16)wv.y;
            wB[cg * 4 + 2][k] = (_Float16)wv.z;
            wB[cg * 4 + 3][k] = (_Float16)wv.w;
        }
    }
    __syncthreads();

    const int wv = t >> 6;                // wave 0..3 -> rows [wv*16, wv*16+16)
    const int lane = t & 63;
    const int fr = lane & 15;             // frag row (A) / col (B,D)
    const int kg8 = (lane >> 4) * 8;      // k chunk base
    f32x4 acc0 = {0.f, 0.f, 0.f, 0.f};
    f32x4 acc1 = {0.f, 0.f, 0.f, 0.f};
    f32x4 acc2 = {0.f, 0.f, 0.f, 0.f};
    f32x4 acc3 = {0.f, 0.f, 0.f, 0.f};

#pragma unroll
    for (int ks = 0; ks < BK; ks += 32) {
        half8 af = *(half8*)&xA[wv * 16 + fr][ks + kg8];
        half8 b0 = *(half8*)&wB[0 * 16 + fr][ks + kg8];
        half8 b1 = *(half8*)&wB[1 * 16 + fr][ks + kg8];
        half8 b2 = *(half8*)&wB[2 * 16 + fr][ks + kg8];
        half8 b3 = *(half8*)&wB[3 * 16 + fr][ks + kg8];
        acc0 = __builtin_amdgcn_mfma_f32_16x16x32_f16(af, b0, acc0, 0, 0, 0);
        acc1 = __builtin_amdgcn_mfma_f32_16x16x32_f16(af, b1, acc1, 0, 0, 0);
        acc2 = __builtin_amdgcn_mfma_f32_16x16x32_f16(af, b2, acc2, 0, 0, 0);
        acc3 = __builtin_amdgcn_mfma_f32_16x16x32_f16(af, b3, acc3, 0, 0, 0);
    }

    // epilogue: D row=(lane>>4)*4+i (A-rows), col=lane&15 (B-cols)
    int r0 = wv * 16 + (lane >> 4) * 4;
    float dv[4];
    bool ok[4];
#pragma unroll
    for (int i = 0; i < 4; ++i) {
        int row = m0 + r0 + i;
        ok[i] = row < M;
        dv[i] = ok[i] ? dinv[row] : 0.f;
    }
    const f32x4* accs[4] = {&acc0, &acc1, &acc2, &acc3};
#pragma unroll
    for (int fc = 0; fc < 4; ++fc) {
        int col = c0 + fc * 16 + fr;
#pragma unroll
        for (int i = 0; i < 4; ++i) {
            if (ok[i]) {
                int row = m0 + r0 + i;
                G[(size_t)row * Ncols + col] = __float2half((*accs[fc])[i] * dv[i]);
            }
        }
    }
}

// ------- agg1 half-row pass: features [p*64, p*64+64), F=128 table -------
__global__ __launch_bounds__(256) void agg_split(
    const __half* __restrict__ G, const int* __restrict__ rowptr,
    const int* __restrict__ colx, const float* __restrict__ dinv,
    const float* __restrict__ bias, __half* __restrict__ Out, int N, int p) {
    constexpr int UNR = 16;
    int wid = (int)((blockIdx.x * 256 + threadIdx.x) >> 6);
    int lane = threadIdx.x & 63;
    if (wid >= N) return;
    int s = rowptr[wid], e = rowptr[wid + 1];
    int emain = s + ((e - s) & ~(UNR - 1));

    const unsigned* gp = (const unsigned*)G;       // row = 64 dwords
    int dw = p * 32 + (lane & 31);
    int half = lane >> 5;                          // 0 or 1

    __half2 z = __floats2half2_rn(0.f, 0.f);
    unsigned su = gp[(size_t)wid * 64 + dw];       // self term (count once)
    __half2 hacc = half ? z : *(__half2*)&su;
    __half2 hacc2 = z;

    for (int j = s; j < emain; j += UNR) {         // exact, unmasked
        int cl = colx[j + (lane & 15)];            // one coalesced load/batch
        unsigned v[UNR / 2];
#pragma unroll
        for (int u = 0; u < UNR; u += 2) {
            int c0 = __builtin_amdgcn_readlane(cl, u);
            int c1 = __builtin_amdgcn_readlane(cl, u + 1);
            int cu = half ? c1 : c0;
            v[u / 2] = gp[(size_t)cu * 64 + dw];
        }
#pragma unroll
        for (int u = 0; u < UNR; u += 4) {
            hacc  = __hadd2(hacc,  *(__half2*)&v[u / 2]);
            hacc2 = __hadd2(hacc2, *(__half2*)&v[u / 2 + 1]);
        }
    }
    if (emain < e) {                               // one masked batch
        int cl = clampN(colx[min(emain + (lane & 15), e - 1)], N);
        const __half2 one2 = __floats2half2_rn(1.f, 1.f);
#pragma unroll
        for (int u = 0; u < UNR; u += 2) {
            int c0 = __builtin_amdgcn_readlane(cl, u);
            int c1 = __builtin_amdgcn_readlane(cl, u + 1);
            int cu = half ? c1 : c0;
            unsigned vv = gp[(size_t)cu * 64 + dw];
            int jj = emain + u + half;
            __half2 w = (jj < e) ? one2 : z;
            hacc = __hfma2(w, *(__half2*)&vv, hacc);
        }
    }

    hacc = __hadd2(hacc, hacc2);
    int bits = *(int*)&hacc;
    int other = __shfl_xor(bits, 32, 64);          // cross-half partial
    __half2 ho = *(__half2*)&other;
    float2 f1 = __half22float2(hacc);
    float2 f2 = __half22float2(ho);
    float ax = f1.x + f2.x, ay = f1.y + f2.y;

    if (half == 0) {
        float d = dinv[wid];
        float2 bv = *(const float2*)&bias[dw * 2];
        float ox = fmaf(d, ax, bv.x);
        float oy = fmaf(d, ay, bv.y);
        ox = fmaxf(ox, 0.f); oy = fmaxf(oy, 0.f);  // relu (layer 1)
        __half2 h = __floats2half2_rn(ox, oy);
        ((unsigned*)Out)[(size_t)wid * 64 + dw] = *(unsigned*)&h;
    }
}

// ------- agg layer-2 (F=64): f16 table, packed accumulate, f32 out -------
template <int UNR>
__global__ __launch_bounds__(256) void agg2_kernel(
    const __half* __restrict__ G, const int* __restrict__ rowptr,
    const int* __restrict__ colx, const float* __restrict__ dinv,
    const float* __restrict__ bias, float* __restrict__ Out, int N) {
    static_assert(UNR == 16, "readlane batch hard-coded to 16");
    int wid = (int)((blockIdx.x * 256 + threadIdx.x) >> 6);
    int lane = threadIdx.x & 63;
    if (wid >= N) return;
    int s = rowptr[wid], e = rowptr[wid + 1];
    int emain = s + ((e - s) & ~(UNR - 1));

    const unsigned* gp = (const unsigned*)G;       // row = 32 dwords
    const int dw = lane & 31;

    unsigned su = gp[((size_t)wid << 5) + dw];     // self term
    __half2 hacc = *(__half2*)&su;
    __half2 hacc2 = __floats2half2_rn(0.f, 0.f);

    for (int j = s; j < emain; j += UNR) {
        int cl = colx[j + (lane & 15)];
        unsigned v[UNR];
#pragma unroll
        for (int u = 0; u < UNR; ++u) {
            int cu = __builtin_amdgcn_readlane(cl, u);
            v[u] = gp[((size_t)cu << 5) + dw];
        }
#pragma unroll
        for (int u = 0; u < UNR; u += 2) {
            hacc  = __hadd2(hacc,  *(__half2*)&v[u]);
            hacc2 = __hadd2(hacc2, *(__half2*)&v[u + 1]);
        }
    }
    if (emain < e) {
        int cl = clampN(colx[min(emain + (lane & 15), e - 1)], N);
        const __half2 one2 = __floats2half2_rn(1.f, 1.f);
        const __half2 zero2 = __floats2half2_rn(0.f, 0.f);
#pragma unroll
        for (int u = 0; u < UNR; ++u) {
            int cu = __builtin_amdgcn_readlane(cl, u);
            unsigned vv = gp[((size_t)cu << 5) + dw];
            __half2 w = (emain + u < e) ? one2 : zero2;
            hacc = __hfma2(w, *(__half2*)&vv, hacc);
        }
    }

    float2 f1 = __half22float2(hacc);
    float2 f2 = __half22float2(hacc2);
    float ax = f1.x + f2.x, ay = f1.y + f2.y;
    float d = dinv[wid];
    if (lane < 32) {
        float2 bv = *(const float2*)&bias[dw * 2];
        float2 o;
        o.x = fmaf(d, ax, bv.x);
        o.y = fmaf(d, ay, bv.y);
        *(float2*)&Out[(size_t)wid * 64 + dw * 2] = o;
    }
}

extern "C" void kernel_launch(void* const* d_in, const int* in_sizes, int n_in,
                              void* d_out, int out_size, void* d_ws, size_t ws_size,
                              hipStream_t stream) {
    const float* x  = (const float*)d_in[0];
    const void*  ei = d_in[1];
    const float* w1 = (const float*)d_in[2];
    const float* b1 = (const float*)d_in[3];
    const float* w2 = (const float*)d_in[4];
    const float* b2 = (const float*)d_in[5];
    float* out = (float*)d_out;

    const int N  = in_sizes[0] / 128;   // 100000
    const int E  = in_sizes[1] / 2;     // 3200000
    const int M  = B * KB;              // cnt matrix cells
    const int NR = (N + B - 1) / B;     // nodes per bucket (<=128)

    char* p = (char*)d_ws;
    auto carve = [&](size_t bytes) {
        void* r = (void*)p;
        p += (bytes + 255) & ~(size_t)255;
        return r;
    };
    int*    cnt      = (int*)carve((size_t)M * 4);
    int*    base     = (int*)carve((size_t)M * 4);
    int*    partials = (int*)carve(1024 * 4);
    int*    flag     = (int*)carve(256);
    int*    rowptr   = (int*)carve((size_t)(N + 1) * 4);
    float*  dinv     = (float*)carve((size_t)N * 4);
    int*    colx     = (int*)carve((size_t)E * 4);
    __half* g1       = (__half*)carve((size_t)N * 128 * 2);  // f16 gather table
    __half* a1       = (__half*)carve((size_t)N * 128 * 2);  // f16 h1
    __half* g2       = g1;          // g1 dead after agg1; reuse
    int*    buck     = (int*)a1;    // packed records dead before agg1 writes a1

    const int EPB = (E + KB - 1) / KB;  // edges per K1/K3 block
    const int NBS = M / 256;            // scan blocks (1024)

    detect_i64<<<1, 64, 0, stream>>>((const int*)ei, flag);
    bucket_count<<<KB, 256, 0, stream>>>(ei, E, EPB, NR, flag, cnt, N);
    scan_partials<<<NBS, 256, 0, stream>>>(cnt, partials, M);
    scan_scan<<<1, 1024, 0, stream>>>(partials, NBS);
    scan_write<<<NBS, 256, 0, stream>>>(cnt, partials, base, M);
    bucket_scatter<<<KB, 256, 0, stream>>>(ei, E, EPB, NR, flag, base, buck, N);
    bucket_csr<<<B, 256, 0, stream>>>(buck, base, E, NR, dinv, rowptr, colx, N);

    // layer 1
    dim3 grid1((N + 63) / 64, 2);
    gemm_mfma<float><<<grid1, 256, 0, stream>>>(x, w1, dinv, g1, N, 128);
    const int aggb = (N + 3) / 4;
    agg_split<<<aggb, 256, 0, stream>>>(g1, rowptr, colx, dinv, b1, a1, N, 0);
    agg_split<<<aggb, 256, 0, stream>>>(g1, rowptr, colx, dinv, b1, a1, N, 1);

    // layer 2
    dim3 grid2((N + 63) / 64, 1);
    gemm_mfma<__half><<<grid2, 256, 0, stream>>>(a1, w2, dinv, g2, N, 64);
    agg2_kernel<16><<<aggb, 256, 0, stream>>>(g2, rowptr, colx, dinv, b2, out, N);
}

// Round 14
// 284.393 us; speedup vs baseline: 1.8446x; 1.0700x over previous
//
#include <hip/hip_runtime.h>
#include <hip/hip_fp16.h>
#include <type_traits>

// 2-layer GCN: h1 = relu(Anorm @ (x@w1) + b1); out = Anorm @ (h1@w2) + b2
// Atomic-free bucket-sort CSR; f16 tables; packed-f16 agg; MFMA GEMMs.
// R13->R14: bucket pipeline widened -- count/scatter use 1024-thread blocks
// (16 waves/CU, was 4) and all three bucket kernels batch-unroll x4
// (independent load/atomic/store chains). scatter was 64us at 6.7%
// occupancy with a serial LDS-atomic->store chain; floor is ~20us.

constexpr int B = 1024;       // dst-range buckets
constexpr int KB = 256;       // blocks in K1/K3

using half8 = __attribute__((ext_vector_type(8))) _Float16;
using f32x4 = __attribute__((ext_vector_type(4))) float;

// ---------------- edge dtype detect (int32 vs int64) ----------------
__global__ void detect_i64(const int* __restrict__ idx32, int* __restrict__ flag) {
    int v = idx32[2 * threadIdx.x + 1];
    unsigned long long b = __ballot(v != 0);
    if (threadIdx.x == 0) flag[0] = (b == 0ULL) ? 1 : 0;
}

__device__ __forceinline__ int load_idx(const void* edges, size_t i, int is64) {
    return is64 ? (int)((const long long*)edges)[i] : ((const int*)edges)[i];
}

__device__ __forceinline__ int clampN(int v, int N) {
    return ((unsigned)v < (unsigned)N) ? v : 0;
}

// ---- K1: per-block bucket histogram (1024 thr, x4 unroll). ----
__global__ __launch_bounds__(1024) void bucket_count(
    const void* __restrict__ edges, int E, int EPB, int NR,
    const int* __restrict__ flag, int* __restrict__ cnt, int N) {
    __shared__ int hist[B];
    int t = threadIdx.x, b = blockIdx.x;
    for (int k = t; k < B; k += 1024) hist[k] = 0;
    __syncthreads();
    int is64 = flag[0];
    int start = b * EPB, end = min(E, start + EPB);
    int j = start + t;
    for (; j + 3 * 1024 < end; j += 4 * 1024) {
        int d[4];
#pragma unroll
        for (int u = 0; u < 4; ++u)
            d[u] = clampN(load_idx(edges, (size_t)E + j + u * 1024, is64), N) / NR;
#pragma unroll
        for (int u = 0; u < 4; ++u) atomicAdd(&hist[d[u]], 1);
    }
    for (; j < end; j += 1024) {
        int d = clampN(load_idx(edges, (size_t)E + j, is64), N);
        atomicAdd(&hist[d / NR], 1);
    }
    __syncthreads();
    for (int k = t; k < B; k += 1024) cnt[(size_t)k * KB + b] = hist[k];
}

// ---------------- 3-kernel exclusive scan (M = B*KB elements) ----------------
__global__ void scan_partials(const int* __restrict__ in, int* __restrict__ partials, int M) {
    __shared__ int sm[256];
    int t = threadIdx.x, i = blockIdx.x * 256 + t;
    sm[t] = (i < M) ? in[i] : 0;
    __syncthreads();
    for (int off = 128; off > 0; off >>= 1) {
        if (t < off) sm[t] += sm[t + off];
        __syncthreads();
    }
    if (t == 0) partials[blockIdx.x] = sm[0];
}

__global__ void scan_scan(int* __restrict__ partials, int NB) {  // 1 block, 1024 thr
    __shared__ int sm[1024];
    int t = threadIdx.x;
    int v = (t < NB) ? partials[t] : 0;
    sm[t] = v; __syncthreads();
    for (int off = 1; off < 1024; off <<= 1) {
        int x = sm[t];
        int y = (t >= off) ? sm[t - off] : 0;
        __syncthreads();
        sm[t] = x + y;
        __syncthreads();
    }
    if (t < NB) partials[t] = (t == 0) ? 0 : sm[t - 1];  // exclusive
}

__global__ void scan_write(const int* __restrict__ in, const int* __restrict__ partials,
                           int* __restrict__ out, int M) {
    __shared__ int sm[256];
    int t = threadIdx.x, b = blockIdx.x, i = b * 256 + t;
    int v = (i < M) ? in[i] : 0;
    sm[t] = v; __syncthreads();
    for (int off = 1; off < 256; off <<= 1) {
        int x = sm[t];
        int y = (t >= off) ? sm[t - off] : 0;
        __syncthreads();
        sm[t] = x + y;
        __syncthreads();
    }
    if (i < M) out[i] = partials[b] + sm[t] - v;  // exclusive
}

// ---- K3: bucketed scatter (1024 thr, x4 unroll); rec = dlocal<<17 | src. ----
__global__ __launch_bounds__(1024) void bucket_scatter(
    const void* __restrict__ edges, int E, int EPB, int NR,
    const int* __restrict__ flag, const int* __restrict__ base,
    int* __restrict__ buck, int N) {
    __shared__ int cur[B];
    int t = threadIdx.x, b = blockIdx.x;
    for (int k = t; k < B; k += 1024) cur[k] = base[(size_t)k * KB + b];
    __syncthreads();
    int is64 = flag[0];
    int start = b * EPB, end = min(E, start + EPB);
    int j = start + t;
    for (; j + 3 * 1024 < end; j += 4 * 1024) {
        int s[4], bin[4], dl[4], pos[4];
#pragma unroll
        for (int u = 0; u < 4; ++u) {
            int jj = j + u * 1024;
            s[u] = clampN(load_idx(edges, (size_t)jj, is64), N);
            int d = clampN(load_idx(edges, (size_t)E + jj, is64), N);
            bin[u] = d / NR;
            dl[u] = d - bin[u] * NR;
        }
#pragma unroll
        for (int u = 0; u < 4; ++u) pos[u] = atomicAdd(&cur[bin[u]], 1);
#pragma unroll
        for (int u = 0; u < 4; ++u) buck[pos[u]] = (dl[u] << 17) | s[u];
    }
    for (; j < end; j += 1024) {
        int s = clampN(load_idx(edges, (size_t)j, is64), N);
        int d = clampN(load_idx(edges, (size_t)E + j, is64), N);
        int bin = d / NR;
        int dl = d - bin * NR;
        int pos = atomicAdd(&cur[bin], 1);
        buck[pos] = (dl << 17) | s;
    }
}

// ---- K4: per-bucket CSR (x4 unroll). LDS count + scan; writes CSR. ----
__global__ __launch_bounds__(256) void bucket_csr(
    const int* __restrict__ buck, const int* __restrict__ base, int E, int NR,
    float* __restrict__ dinv, int* __restrict__ rowptr,
    int* __restrict__ colx, int N) {
    __shared__ int hist[128];  // NR <= 128
    __shared__ int cnt0[128];
    __shared__ int cur[128];
    int t = threadIdx.x, b = blockIdx.x;
    if (b == 0 && t == 0) rowptr[N] = E;
    int d0 = b * NR;
    if (d0 >= N) return;
    int nr = min(NR, N - d0);
    int segbase = base[(size_t)b * KB];
    int segend = (b == B - 1) ? E : base[(size_t)(b + 1) * KB];

    if (t < 128) hist[t] = 0;
    __syncthreads();
    {
        int j = segbase + t;
        for (; j + 3 * 256 < segend; j += 4 * 256) {
            int v[4];
#pragma unroll
            for (int u = 0; u < 4; ++u) v[u] = buck[j + u * 256] >> 17;
#pragma unroll
            for (int u = 0; u < 4; ++u) atomicAdd(&hist[v[u]], 1);
        }
        for (; j < segend; j += 256) atomicAdd(&hist[buck[j] >> 17], 1);
    }
    __syncthreads();
    if (t < 128) cnt0[t] = hist[t];
    __syncthreads();
    for (int off = 1; off < 128; off <<= 1) {  // inclusive scan
        int v = 0;
        if (t < 128 && t >= off) v = hist[t - off];
        __syncthreads();
        if (t < 128) hist[t] += v;
        __syncthreads();
    }
    if (t < 128) {
        int ex = hist[t] - cnt0[t];  // exclusive
        cur[t] = ex;
        if (t < nr) {
            rowptr[d0 + t] = segbase + ex;
            dinv[d0 + t] = rsqrtf((float)(cnt0[t] + 1));  // +1 self-loop
        }
    }
    __syncthreads();
    {
        int j = segbase + t;
        for (; j + 3 * 256 < segend; j += 4 * 256) {
            int v[4], pos[4];
#pragma unroll
            for (int u = 0; u < 4; ++u) v[u] = buck[j + u * 256];
#pragma unroll
            for (int u = 0; u < 4; ++u) pos[u] = atomicAdd(&cur[v[u] >> 17], 1);
#pragma unroll
            for (int u = 0; u < 4; ++u) colx[segbase + pos[u]] = v[u] & 0x1FFFF;
        }
        for (; j < segend; j += 256) {
            int v = buck[j];
            int pos = segbase + atomicAdd(&cur[v >> 17], 1);
            colx[pos] = v & 0x1FFFF;
        }
    }
}

// ------- MFMA GEMM: G = f16( dinv .* (X @ W) ), K=128; X f32 or f16 -------
template <typename XT>
__global__ __launch_bounds__(256) void gemm_mfma(
    const XT* __restrict__ X, const float* __restrict__ W,
    const float* __restrict__ dinv, __half* __restrict__ G, int M, int Ncols) {
    constexpr int BK = 128;
    constexpr int LDP = BK + 8;           // padded stride (f16)
    __shared__ _Float16 xA[64][LDP];      // [row][k]
    __shared__ _Float16 wB[64][LDP];      // [col][k]
    const int t = threadIdx.x;
    const int m0 = blockIdx.x * 64;
    const int c0 = blockIdx.y * 64;

    {
        int r = t & 63, kg = t >> 6;
        int row = m0 + r; if (row >= M) row = M - 1;
        const XT* xr = &X[(size_t)row * BK + kg * 32];
        if constexpr (std::is_same<XT, __half>::value) {
            const uint4* src = (const uint4*)xr;
            uint4* dst = (uint4*)&xA[r][kg * 32];
#pragma unroll
            for (int q = 0; q < 4; ++q) dst[q] = src[q];
        } else {
#pragma unroll
            for (int c = 0; c < 32; c += 8) {
                float4 a = *(const float4*)&xr[c];
                float4 b = *(const float4*)&xr[c + 4];
                half8 h;
                h[0] = (_Float16)a.x; h[1] = (_Float16)a.y;
                h[2] = (_Float16)a.z; h[3] = (_Float16)a.w;
                h[4] = (_Float16)b.x; h[5] = (_Float16)b.y;
                h[6] = (_Float16)b.z; h[7] = (_Float16)b.w;
                *(half8*)&xA[r][kg * 32 + c] = h;
            }
        }
    }
    {
        int cg = t & 15, k0 = t >> 4;
#pragma unroll
        for (int kk = 0; kk < 8; ++kk) {
            int k = k0 + kk * 16;
            float4 wv = *(const float4*)&W[(size_t)k * Ncols + c0 + cg * 4];
            wB[cg * 4 + 0][k] = (_Float16)wv.x;
            wB[cg * 4 + 1][k] = (_Float16)wv.y;
            wB[cg * 4 + 2][k] = (_Float16)wv.z;
            wB[cg * 4 + 3][k] = (_Float16)wv.w;
        }
    }
    __syncthreads();

    const int wv = t >> 6;
    const int lane = t & 63;
    const int fr = lane & 15;
    const int kg8 = (lane >> 4) * 8;
    f32x4 acc0 = {0.f, 0.f, 0.f, 0.f};
    f32x4 acc1 = {0.f, 0.f, 0.f, 0.f};
    f32x4 acc2 = {0.f, 0.f, 0.f, 0.f};
    f32x4 acc3 = {0.f, 0.f, 0.f, 0.f};

#pragma unroll
    for (int ks = 0; ks < BK; ks += 32) {
        half8 af = *(half8*)&xA[wv * 16 + fr][ks + kg8];
        half8 b0 = *(half8*)&wB[0 * 16 + fr][ks + kg8];
        half8 b1 = *(half8*)&wB[1 * 16 + fr][ks + kg8];
        half8 b2 = *(half8*)&wB[2 * 16 + fr][ks + kg8];
        half8 b3 = *(half8*)&wB[3 * 16 + fr][ks + kg8];
        acc0 = __builtin_amdgcn_mfma_f32_16x16x32_f16(af, b0, acc0, 0, 0, 0);
        acc1 = __builtin_amdgcn_mfma_f32_16x16x32_f16(af, b1, acc1, 0, 0, 0);
        acc2 = __builtin_amdgcn_mfma_f32_16x16x32_f16(af, b2, acc2, 0, 0, 0);
        acc3 = __builtin_amdgcn_mfma_f32_16x16x32_f16(af, b3, acc3, 0, 0, 0);
    }

    int r0 = wv * 16 + (lane >> 4) * 4;
    float dv[4];
    bool ok[4];
#pragma unroll
    for (int i = 0; i < 4; ++i) {
        int row = m0 + r0 + i;
        ok[i] = row < M;
        dv[i] = ok[i] ? dinv[row] : 0.f;
    }
    const f32x4* accs[4] = {&acc0, &acc1, &acc2, &acc3};
#pragma unroll
    for (int fc = 0; fc < 4; ++fc) {
        int col = c0 + fc * 16 + fr;
#pragma unroll
        for (int i = 0; i < 4; ++i) {
            if (ok[i]) {
                int row = m0 + r0 + i;
                G[(size_t)row * Ncols + col] = __float2half((*accs[fc])[i] * dv[i]);
            }
        }
    }
}

// ------- agg1 half-row pass: features [p*64, p*64+64), F=128 table -------
__global__ __launch_bounds__(256) void agg_split(
    const __half* __restrict__ G, const int* __restrict__ rowptr,
    const int* __restrict__ colx, const float* __restrict__ dinv,
    const float* __restrict__ bias, __half* __restrict__ Out, int N, int p) {
    constexpr int UNR = 16;
    int wid = (int)((blockIdx.x * 256 + threadIdx.x) >> 6);
    int lane = threadIdx.x & 63;
    if (wid >= N) return;
    int s = rowptr[wid], e = rowptr[wid + 1];
    int emain = s + ((e - s) & ~(UNR - 1));

    const unsigned* gp = (const unsigned*)G;       // row = 64 dwords
    int dw = p * 32 + (lane & 31);
    int half = lane >> 5;                          // 0 or 1

    __half2 z = __floats2half2_rn(0.f, 0.f);
    unsigned su = gp[(size_t)wid * 64 + dw];       // self term (count once)
    __half2 hacc = half ? z : *(__half2*)&su;
    __half2 hacc2 = z;

    for (int j = s; j < emain; j += UNR) {         // exact, unmasked
        int cl = colx[j + (lane & 15)];            // one coalesced load/batch
        unsigned v[UNR / 2];
#pragma unroll
        for (int u = 0; u < UNR; u += 2) {
            int c0 = __builtin_amdgcn_readlane(cl, u);
            int c1 = __builtin_amdgcn_readlane(cl, u + 1);
            int cu = half ? c1 : c0;
            v[u / 2] = gp[(size_t)cu * 64 + dw];
        }
#pragma unroll
        for (int u = 0; u < UNR; u += 4) {
            hacc  = __hadd2(hacc,  *(__half2*)&v[u / 2]);
            hacc2 = __hadd2(hacc2, *(__half2*)&v[u / 2 + 1]);
        }
    }
    if (emain < e) {                               // one masked batch
        int cl = clampN(colx[min(emain + (lane & 15), e - 1)], N);
        const __half2 one2 = __floats2half2_rn(1.f, 1.f);
#pragma unroll
        for (int u = 0; u < UNR; u += 2) {
            int c0 = __builtin_amdgcn_readlane(cl, u);
            int c1 = __builtin_amdgcn_readlane(cl, u + 1);
            int cu = half ? c1 : c0;
            unsigned vv = gp[(size_t)cu * 64 + dw];
            int jj = emain + u + half;
            __half2 w = (jj < e) ? one2 : z;
            hacc = __hfma2(w, *(__half2*)&vv, hacc);
        }
    }

    hacc = __hadd2(hacc, hacc2);
    int bits = *(int*)&hacc;
    int other = __shfl_xor(bits, 32, 64);          // cross-half partial
    __half2 ho = *(__half2*)&other;
    float2 f1 = __half22float2(hacc);
    float2 f2 = __half22float2(ho);
    float ax = f1.x + f2.x, ay = f1.y + f2.y;

    if (half == 0) {
        float d = dinv[wid];
        float2 bv = *(const float2*)&bias[dw * 2];
        float ox = fmaf(d, ax, bv.x);
        float oy = fmaf(d, ay, bv.y);
        ox = fmaxf(ox, 0.f); oy = fmaxf(oy, 0.f);  // relu (layer 1)
        __half2 h = __floats2half2_rn(ox, oy);
        ((unsigned*)Out)[(size_t)wid * 64 + dw] = *(unsigned*)&h;
    }
}

// ------- agg layer-2 (F=64): f16 table, packed accumulate, f32 out -------
template <int UNR>
__global__ __launch_bounds__(256) void agg2_kernel(
    const __half* __restrict__ G, const int* __restrict__ rowptr,
    const int* __restrict__ colx, const float* __restrict__ dinv,
    const float* __restrict__ bias, float* __restrict__ Out, int N) {
    static_assert(UNR == 16, "readlane batch hard-coded to 16");
    int wid = (int)((blockIdx.x * 256 + threadIdx.x) >> 6);
    int lane = threadIdx.x & 63;
    if (wid >= N) return;
    int s = rowptr[wid], e = rowptr[wid + 1];
    int emain = s + ((e - s) & ~(UNR - 1));

    const unsigned* gp = (const unsigned*)G;       // row = 32 dwords
    const int dw = lane & 31;

    unsigned su = gp[((size_t)wid << 5) + dw];     // self term
    __half2 hacc = *(__half2*)&su;
    __half2 hacc2 = __floats2half2_rn(0.f, 0.f);

    for (int j = s; j < emain; j += UNR) {
        int cl = colx[j + (lane & 15)];
        unsigned v[UNR];
#pragma unroll
        for (int u = 0; u < UNR; ++u) {
            int cu = __builtin_amdgcn_readlane(cl, u);
            v[u] = gp[((size_t)cu << 5) + dw];
        }
#pragma unroll
        for (int u = 0; u < UNR; u += 2) {
            hacc  = __hadd2(hacc,  *(__half2*)&v[u]);
            hacc2 = __hadd2(hacc2, *(__half2*)&v[u + 1]);
        }
    }
    if (emain < e) {
        int cl = clampN(colx[min(emain + (lane & 15), e - 1)], N);
        const __half2 one2 = __floats2half2_rn(1.f, 1.f);
        const __half2 zero2 = __floats2half2_rn(0.f, 0.f);
#pragma unroll
        for (int u = 0; u < UNR; ++u) {
            int cu = __builtin_amdgcn_readlane(cl, u);
            unsigned vv = gp[((size_t)cu << 5) + dw];
            __half2 w = (emain + u < e) ? one2 : zero2;
            hacc = __hfma2(w, *(__half2*)&vv, hacc);
        }
    }

    float2 f1 = __half22float2(hacc);
    float2 f2 = __half22float2(hacc2);
    float ax = f1.x + f2.x, ay = f1.y + f2.y;
    float d = dinv[wid];
    if (lane < 32) {
        float2 bv = *(const float2*)&bias[dw * 2];
        float2 o;
        o.x = fmaf(d, ax, bv.x);
        o.y = fmaf(d, ay, bv.y);
        *(float2*)&Out[(size_t)wid * 64 + dw * 2] = o;
    }
}

extern "C" void kernel_launch(void* const* d_in, const int* in_sizes, int n_in,
                              void* d_out, int out_size, void* d_ws, size_t ws_size,
                              hipStream_t stream) {
    const float* x  = (const float*)d_in[0];
    const void*  ei = d_in[1];
    const float* w1 = (const float*)d_in[2];
    const float* b1 = (const float*)d_in[3];
    const float* w2 = (const float*)d_in[4];
    const float* b2 = (const float*)d_in[5];
    float* out = (float*)d_out;

    const int N  = in_sizes[0] / 128;   // 100000
    const int E  = in_sizes[1] / 2;     // 3200000
    const int M  = B * KB;              // cnt matrix cells
    const int NR = (N + B - 1) / B;     // nodes per bucket (<=128)

    char* p = (char*)d_ws;
    auto carve = [&](size_t bytes) {
        void* r = (void*)p;
        p += (bytes + 255) & ~(size_t)255;
        return r;
    };
    int*    cnt      = (int*)carve((size_t)M * 4);
    int*    base     = (int*)carve((size_t)M * 4);
    int*    partials = (int*)carve(1024 * 4);
    int*    flag     = (int*)carve(256);
    int*    rowptr   = (int*)carve((size_t)(N + 1) * 4);
    float*  dinv     = (float*)carve((size_t)N * 4);
    int*    colx     = (int*)carve((size_t)E * 4);
    __half* g1       = (__half*)carve((size_t)N * 128 * 2);  // f16 gather table
    __half* a1       = (__half*)carve((size_t)N * 128 * 2);  // f16 h1
    __half* g2       = g1;          // g1 dead after agg1; reuse
    int*    buck     = (int*)a1;    // packed records dead before agg1 writes a1

    const int EPB = (E + KB - 1) / KB;  // edges per K1/K3 block
    const int NBS = M / 256;            // scan blocks (1024)

    detect_i64<<<1, 64, 0, stream>>>((const int*)ei, flag);
    bucket_count<<<KB, 1024, 0, stream>>>(ei, E, EPB, NR, flag, cnt, N);
    scan_partials<<<NBS, 256, 0, stream>>>(cnt, partials, M);
    scan_scan<<<1, 1024, 0, stream>>>(partials, NBS);
    scan_write<<<NBS, 256, 0, stream>>>(cnt, partials, base, M);
    bucket_scatter<<<KB, 1024, 0, stream>>>(ei, E, EPB, NR, flag, base, buck, N);
    bucket_csr<<<B, 256, 0, stream>>>(buck, base, E, NR, dinv, rowptr, colx, N);

    // layer 1
    dim3 grid1((N + 63) / 64, 2);
    gemm_mfma<float><<<grid1, 256, 0, stream>>>(x, w1, dinv, g1, N, 128);
    const int aggb = (N + 3) / 4;
    agg_split<<<aggb, 256, 0, stream>>>(g1, rowptr, colx, dinv, b1, a1, N, 0);
    agg_split<<<aggb, 256, 0, stream>>>(g1, rowptr, colx, dinv, b1, a1, N, 1);

    // layer 2
    dim3 grid2((N + 63) / 64, 1);
    gemm_mfma<__half><<<grid2, 256, 0, stream>>>(a1, w2, dinv, g2, N, 64);
    agg2_kernel<16><<<aggb, 256, 0, stream>>>(g2, rowptr, colx, dinv, b2, out, N);
}